// Round 10
// baseline (4759.385 us; speedup 1.0000x reference)
//
#include <hip/hip_runtime.h>
#include <hip/hip_bf16.h>

// GINet forward, fp32 in/out. R10: strip-GEMM (k_smm) — each block stages a
// 64-row A strip's FULL K into LDS once (KPAD odd-16B-line stride), loops col
// tiles with B direct from L2-hot packed weights => A HBM traffic exactly 1x.
// Last-layer BN folded into k_hgdiv (affine commutes with mean-pool).

#define NN   100000
#define EE   200000
#define GG   2000
#define DD   300
#define D2   600
#define LL   5
#define FEATN 512
#define OUT2 256
#define ROWS_PER 256

typedef __hip_bfloat16 bf16;
typedef short vec8s __attribute__((ext_vector_type(8)));
typedef float vec4f __attribute__((ext_vector_type(4)));

__device__ __forceinline__ short f2bs(float v) {
    bf16 h = __float2bfloat16(v);
    return __builtin_bit_cast(short, h);
}

// ---- weight prepack: src[K][N] fp32 -> dst[kt][col<NPAD][32] bf16 ----
__global__ void k_pack(const float* __restrict__ src, short* __restrict__ dst,
                       int Ksrc, int Nsrc, int KT, int NPAD)
{
    int idx = blockIdx.x * 256 + threadIdx.x;
    int total = KT * NPAD * 32;
    if (idx >= total) return;
    int col = idx % NPAD;
    int tmp = idx / NPAD;
    int kk  = tmp % 32;
    int kt  = tmp / 32;
    int k = kt * 32 + kk;
    short v = 0;
    if (k < Ksrc && col < Nsrc) v = f2bs(src[(size_t)k * Nsrc + col]);
    dst[((size_t)kt * NPAD + col) * 32 + kk] = v;
}

// ---- strip MFMA GEMM: 64-row strip/block, full-K A in LDS, col-tile loop ----
// KPAD: LDS row length in shorts, must be ≡ 8 (mod 16) for bank spread.
template<int A_BF, int OUT_BF_RELU, int KPAD>
__global__ __launch_bounds__(256) void k_smm(
    const void* __restrict__ A, int lda, int K,
    const short* __restrict__ WP, int npad,
    const float* __restrict__ bias,
    void* __restrict__ out, int ldo, int N, int M, int NCT)
{
    __shared__ __align__(16) short As[64][KPAD];
    const int t = threadIdx.x;
    const int wv = t >> 6, lane = t & 63;
    const int m = lane & 15, quad = lane >> 4;
    const int rb = (int)blockIdx.x * 64;
    const int KT = (K + 31) / 32;
    const int GR = KPAD / 8;

    // stage full A strip (64 x K, zero-padded to KPAD)
    for (int g = t; g < 64 * GR; g += 256) {
        int r = g / GR, c8 = g % GR;
        int ks = c8 * 8;
        int grow = rb + r;
        vec8s v = (vec8s)0;
        if (grow < M && ks < K) {
            if (A_BF) {
                const short* ap = (const short*)A + (size_t)grow * lda + ks;
                if (ks + 8 <= K) v = *(const vec8s*)ap;
                else {
#pragma unroll
                    for (int j = 0; j < 8; j++)
                        v[j] = (ks + j < K) ? ap[j] : (short)0;
                }
            } else {
                const float* ap = (const float*)A + (size_t)grow * lda + ks;
                if (ks + 8 <= K) {
                    vec4f p0 = *(const vec4f*)ap;
                    vec4f p1 = *(const vec4f*)(ap + 4);
                    v[0] = f2bs(p0[0]); v[1] = f2bs(p0[1]);
                    v[2] = f2bs(p0[2]); v[3] = f2bs(p0[3]);
                    v[4] = f2bs(p1[0]); v[5] = f2bs(p1[1]);
                    v[6] = f2bs(p1[2]); v[7] = f2bs(p1[3]);
                } else {
#pragma unroll
                    for (int j = 0; j < 8; j++)
                        v[j] = (ks + j < K) ? f2bs(ap[j]) : (short)0;
                }
            }
        }
        *(vec8s*)&As[r][ks] = v;
    }
    __syncthreads();

    for (int ct = 0; ct < NCT; ct++) {
        int cb = ct * 128;
        vec4f acc[8];
#pragma unroll
        for (int cf = 0; cf < 8; cf++) acc[cf] = (vec4f)0.f;

        for (int kt = 0; kt < KT; kt++) {
            vec8s af = *(vec8s*)&As[wv * 16 + m][kt * 32 + quad * 8];
            const short* wbase = WP + ((size_t)kt * npad + cb + m) * 32 + quad * 8;
#pragma unroll
            for (int cf = 0; cf < 8; cf++) {
                vec8s bfr = *(const vec8s*)(wbase + (size_t)cf * 16 * 32);
                acc[cf] = __builtin_amdgcn_mfma_f32_16x16x32_bf16(af, bfr, acc[cf], 0, 0, 0);
            }
        }
        // epilogue: C/D col=lane&15, row=quad*4+reg (HW-validated)
#pragma unroll
        for (int cf = 0; cf < 8; cf++) {
            int gc = cb + cf * 16 + m;
            if (gc >= N) continue;
            float bv = bias[gc];
#pragma unroll
            for (int reg = 0; reg < 4; reg++) {
                int grow = rb + wv * 16 + quad * 4 + reg;
                if (grow < M) {
                    float v = acc[cf][reg] + bv;
                    if (OUT_BF_RELU)
                        ((short*)out)[(size_t)grow * ldo + gc] = f2bs(fmaxf(v, 0.f));
                    else
                        ((float*)out)[(size_t)grow * ldo + gc] = v;
                }
            }
        }
    }
}

// ============ CSR build ============
__global__ void k_degree(const int* __restrict__ dst, int* __restrict__ deg) {
    int e = blockIdx.x * 256 + threadIdx.x;
    if (e < EE) atomicAdd(&deg[dst[e]], 1);
}

__global__ void k_scan1(const int* __restrict__ deg, int* __restrict__ off,
                        int* __restrict__ bsum)
{
    __shared__ int s[256];
    int i = blockIdx.x * 256 + threadIdx.x;
    int v = (i < NN) ? deg[i] : 0;
    s[threadIdx.x] = v;
    __syncthreads();
    for (int o = 1; o < 256; o <<= 1) {
        int tv = (threadIdx.x >= o) ? s[threadIdx.x - o] : 0;
        __syncthreads();
        s[threadIdx.x] += tv;
        __syncthreads();
    }
    if (i < NN) off[i] = s[threadIdx.x] - v;
    if (threadIdx.x == 255) bsum[blockIdx.x] = s[255];
}

__global__ void k_scan2(int* __restrict__ bsum, int* __restrict__ off, int nb) {
    if (threadIdx.x != 0 || blockIdx.x != 0) return;
    int run = 0;
    for (int b = 0; b < nb; b++) { int t = bsum[b]; bsum[b] = run; run += t; }
    off[NN] = run;
}

__global__ void k_scan3(int* __restrict__ off, const int* __restrict__ bsum,
                        int* __restrict__ curs)
{
    int i = blockIdx.x * 256 + threadIdx.x;
    if (i >= NN) return;
    int v = off[i] + bsum[i >> 8];
    off[i] = v;
    curs[i] = v;
}

__global__ void k_fill(const int* __restrict__ dst, int* __restrict__ curs,
                       int* __restrict__ eidx)
{
    int e = blockIdx.x * 256 + threadIdx.x;
    if (e >= EE) return;
    int pos = atomicAdd(&curs[dst[e]], 1);
    eidx[pos] = e;
}

// ============ embed attention ============
__global__ __launch_bounds__(256) void k_embed(
    const int* __restrict__ x, const float* __restrict__ atom_emb,
    const float* __restrict__ att_vec, float* __restrict__ fused)
{
    int wave = threadIdx.x >> 6;
    int lane = threadIdx.x & 63;
    int n = blockIdx.x * 4 + wave;
    if (n >= NN) return;

    float att[5];
#pragma unroll
    for (int j = 0; j < 5; j++) {
        int d = lane + 64 * j;
        att[j] = (d < DD) ? att_vec[d] : 0.f;
    }
    float emb[9][5];
    float sc[9];
#pragma unroll
    for (int f = 0; f < 9; f++) {
        int idx = x[n * 9 + f];
        const float* p = atom_emb + (size_t)(f * 119 + idx) * DD;
        float partial = 0.f;
#pragma unroll
        for (int j = 0; j < 5; j++) {
            int d = lane + 64 * j;
            float v = (d < DD) ? p[d] : 0.f;
            emb[f][j] = v;
            partial += v * att[j];
        }
#pragma unroll
        for (int off = 32; off; off >>= 1) partial += __shfl_xor(partial, off, 64);
        sc[f] = partial;
    }
    float mx = sc[0];
#pragma unroll
    for (int f = 1; f < 9; f++) mx = fmaxf(mx, sc[f]);
    float s = 0.f;
#pragma unroll
    for (int f = 0; f < 9; f++) { sc[f] = __expf(sc[f] - mx); s += sc[f]; }
    float inv = 1.f / s;
#pragma unroll
    for (int j = 0; j < 5; j++) {
        int d = lane + 64 * j;
        if (d < DD) {
            float acc = 0.f;
#pragma unroll
            for (int f = 0; f < 9; f++) acc += emb[f][j] * sc[f];
            fused[(size_t)n * DD + d] = acc * inv;
        }
    }
}

// ---- gaussian basis, CSR gather ----
__global__ __launch_bounds__(320) void k_gaussg(
    const int* __restrict__ off, const int* __restrict__ eidx,
    const float* __restrict__ dist, const float* __restrict__ g_means,
    const float* __restrict__ g_stds, const float* __restrict__ scale_p,
    float* __restrict__ H)
{
    int n = blockIdx.x;
    int d = threadIdx.x;
    if (d >= DD) return;
    int beg = off[n], end = off[n + 1];
    if (beg == end) return;
    float sd = fabsf(g_stds[d]) + 0.01f;
    float mean = g_means[d];
    float inv_asd = 1.f / (2.5066263f * sd);
    float sum = 0.f;
    for (int i = beg; i < end; i++) {
        float xv = dist[eidx[i]];
        float z = (xv - mean) / sd;
        sum += __expf(-0.5f * z * z) * inv_asd;
    }
    int deg = end - beg;
    int c = deg - 1; c = c < 0 ? 0 : (c > 3 ? 3 : c);
    H[(size_t)n * DD + d] += __expf(scale_p[c * DD + d]) * sum;
}

// ---- fused aggregation with folded BN+ReLU of previous layer ----
__global__ __launch_bounds__(320) void k_agg(
    const float* __restrict__ P, const int* __restrict__ off,
    const int* __restrict__ eidx, const int* __restrict__ src,
    const int* __restrict__ attr,
    const float* __restrict__ e0, const float* __restrict__ e1,
    const float* __restrict__ e2,
    const float* __restrict__ scale, const float* __restrict__ shift,
    int apply, float* __restrict__ Q)
{
    int n = blockIdx.x;
    int d = threadIdx.x;
    if (d >= DD) return;
    float sc = apply ? scale[d] : 1.f;
    float sh = apply ? shift[d] : 0.f;
    float self = P[(size_t)n * DD + d];
    if (apply) self = fmaxf(self * sc + sh, 0.f);
    float acc = self + e0[4 * DD + d] + e1[d] + e2[d];
    int beg = off[n], end = off[n + 1];
    for (int i = beg; i < end; i++) {
        int e = eidx[i];
        int s = src[e];
        int a0 = attr[e * 3], a1 = attr[e * 3 + 1], a2 = attr[e * 3 + 2];
        float v = P[(size_t)s * DD + d];
        if (apply) v = fmaxf(v * sc + sh, 0.f);
        acc += v + e0[(size_t)a0 * DD + d] + e1[(size_t)a1 * DD + d]
                 + e2[(size_t)a2 * DD + d];
    }
    Q[(size_t)n * DD + d] = acc;
}

// ============ BN ============
__global__ __launch_bounds__(320) void k_stats(const float* __restrict__ H,
                                               float* __restrict__ sum,
                                               float* __restrict__ sumsq)
{
    int d = threadIdx.x;
    if (d >= DD) return;
    int r0 = blockIdx.x * ROWS_PER;
    int rend = min(r0 + ROWS_PER, NN);
    float s = 0.f, sq = 0.f;
    for (int r = r0; r < rend; r++) {
        float v = H[(size_t)r * DD + d];
        s += v; sq += v * v;
    }
    atomicAdd(&sum[d], s);
    atomicAdd(&sumsq[d], sq);
}

__global__ void k_bnprep(float* __restrict__ sum, float* __restrict__ sumsq,
                         const float* __restrict__ gamma,
                         const float* __restrict__ beta)
{
    int d = threadIdx.x + blockIdx.x * 256;
    if (d >= DD) return;
    float mu = sum[d] * (1.f / NN);
    float var = sumsq[d] * (1.f / NN) - mu * mu;
    var = fmaxf(var, 0.f);
    float sc = gamma[d] * rsqrtf(var + 1e-5f);
    sum[d] = sc;
    sumsq[d] = beta[d] - mu * sc;
}

// ============ pooling + head ============
__global__ void k_count(const int* __restrict__ batch, float* __restrict__ cnt) {
    int n = blockIdx.x * 256 + threadIdx.x;
    if (n < NN) atomicAdd(&cnt[batch[n]], 1.0f);
}

__global__ __launch_bounds__(320) void k_pool(const float* __restrict__ H,
                                              const int* __restrict__ batch,
                                              float* __restrict__ HG)
{
    __shared__ int sb[ROWS_PER];
    int r0 = blockIdx.x * ROWS_PER;
    int rend = min(r0 + ROWS_PER, NN);
    for (int i = threadIdx.x; i < rend - r0; i += 320) sb[i] = batch[r0 + i];
    __syncthreads();
    int d = threadIdx.x;
    if (d >= DD) return;
    int cur = sb[0];
    float acc = 0.f;
    for (int r = r0; r < rend; r++) {
        int b = sb[r - r0];
        if (b != cur) { atomicAdd(&HG[(size_t)cur * DD + d], acc); acc = 0.f; cur = b; }
        acc += H[(size_t)r * DD + d];
    }
    atomicAdd(&HG[(size_t)cur * DD + d], acc);
}

// HG = (HG/cnt)*scale + shift  (last-layer BN folded; affine commutes w/ mean)
__global__ void k_hgdiv(float* __restrict__ HG, const float* __restrict__ cnt,
                        const float* __restrict__ scale,
                        const float* __restrict__ shift)
{
    int idx = blockIdx.x * 256 + threadIdx.x;
    if (idx >= GG * DD) return;
    int d = idx % DD;
    float mean = HG[idx] / fmaxf(cnt[idx / DD], 1.0f);
    HG[idx] = mean * scale[d] + shift[d];
}

__global__ __launch_bounds__(256) void k_gemm(
    const float* __restrict__ A, const float* __restrict__ W,
    const float* __restrict__ bias, float* __restrict__ Cf,
    float* __restrict__ Cout, int M, int K, int Ncol, int relu)
{
    extern __shared__ float Ash[];
    int tx = threadIdx.x & 15;
    int ty = threadIdx.x >> 4;
    int rb = blockIdx.y * 16;
    int col = blockIdx.x * 16 + tx;

    for (int idx = threadIdx.x; idx < 16 * K; idx += 256) {
        int r = idx / K, k = idx - r * K;
        int row = rb + r;
        Ash[idx] = (row < M) ? A[(size_t)row * K + k] : 0.f;
    }
    __syncthreads();

    if (col < Ncol) {
        float acc = bias[col];
        const float* a = Ash + ty * K;
        const float* w = W + col;
        for (int k = 0; k < K; k++) acc += a[k] * w[(size_t)k * Ncol];
        if (relu) acc = fmaxf(acc, 0.f);
        int row = rb + ty;
        if (row < M) {
            if (Cf)   Cf[(size_t)row * Ncol + col] = acc;
            if (Cout) Cout[(size_t)row * Ncol + col] = acc;
        }
    }
}

extern "C" void kernel_launch(void* const* d_in, const int* in_sizes, int n_in,
                              void* d_out, int out_size, void* d_ws, size_t ws_size,
                              hipStream_t stream)
{
    const int*   x          = (const int*)  d_in[0];
    const int*   edge_index = (const int*)  d_in[1];
    const int*   edge_attr  = (const int*)  d_in[2];
    const float* edge_dist  = (const float*)d_in[3];
    const int*   batch      = (const int*)  d_in[4];
    const float* atom_emb   = (const float*)d_in[5];
    const float* att_vec    = (const float*)d_in[6];
    const float* out_lin_w  = (const float*)d_in[7];
    const float* out_lin_b  = (const float*)d_in[8];
    const float* g_means    = (const float*)d_in[9];
    const float* g_stds     = (const float*)d_in[10];
    const float* scale_p    = (const float*)d_in[11];
    const float* edge_emb   = (const float*)d_in[12];
    const float* mlp_w1     = (const float*)d_in[13];
    const float* mlp_b1     = (const float*)d_in[14];
    const float* mlp_w2     = (const float*)d_in[15];
    const float* mlp_b2     = (const float*)d_in[16];
    const float* bn_gamma   = (const float*)d_in[17];
    const float* bn_beta    = (const float*)d_in[18];
    const float* feat_w     = (const float*)d_in[19];
    const float* feat_b     = (const float*)d_in[20];
    const float* ol_w1      = (const float*)d_in[21];
    const float* ol_b1      = (const float*)d_in[22];
    const float* ol_w2      = (const float*)d_in[23];
    const float* ol_b2      = (const float*)d_in[24];
    (void)in_sizes; (void)n_in; (void)out_size; (void)ws_size;

    const int* srcp = edge_index;
    const int* dstp = edge_index + EE;

    char* ws = (char*)d_ws;
    size_t off_b = 0;
    auto alloc = [&](size_t bytes) -> char* {
        char* p = ws + off_b;
        off_b += (bytes + 255) & ~(size_t)255;
        return p;
    };
    float* H     = (float*)alloc((size_t)NN * DD * 4);
    float* AGG   = (float*)alloc((size_t)NN * DD * 4);
    int*   DEG   = (int*)  alloc((size_t)NN * 4);
    float* SUM   = (float*)alloc(DD * 4);
    float* SUMQ  = (float*)alloc(DD * 4);
    float* CNT   = (float*)alloc(GG * 4);
    float* HG    = (float*)alloc((size_t)GG * DD * 4);     // } pool 10,592,000 B
    float* HFEAT = (float*)alloc((size_t)GG * FEATN * 4);  // } packed W + CSR
    float* TMP   = (float*)alloc((size_t)GG * FEATN * 4);  // } during loop

    short* OLWP = (short*)HG;                        //   245,760 B
    short* W1P  = OLWP + (size_t)10 * 384 * 32;      // 2,048,000 B
    short* W2P  = W1P + (size_t)LL * 10 * 640 * 32;  // 2,334,720 B
    char*  csr  = (char*)(W2P + (size_t)LL * 19 * 384 * 32);
    int*   OFF  = (int*)csr;
    int*   CURS = (int*)(csr + 400128);
    int*   EIDX = (int*)(csr + 800128);
    int*   BSUM = (int*)CNT;

    float* outp = (float*)d_out;

    // prepack weights
    k_pack<<<480, 256, 0, stream>>>(out_lin_w, OLWP, 300, 300, 10, 384);
    for (int l = 0; l < LL; l++) {
        k_pack<<<800, 256, 0, stream>>>(mlp_w1 + (size_t)l * DD * D2,
                                        W1P + (size_t)l * 10 * 640 * 32, DD, D2, 10, 640);
        k_pack<<<912, 256, 0, stream>>>(mlp_w2 + (size_t)l * D2 * DD,
                                        W2P + (size_t)l * 19 * 384 * 32, D2, DD, 19, 384);
    }

    // CSR build
    hipMemsetAsync(DEG, 0, (size_t)NN * 4, stream);
    k_degree<<<(EE + 255) / 256, 256, 0, stream>>>(dstp, DEG);
    k_scan1<<<391, 256, 0, stream>>>(DEG, OFF, BSUM);
    k_scan2<<<1, 64, 0, stream>>>(BSUM, OFF, 391);
    k_scan3<<<391, 256, 0, stream>>>(OFF, BSUM, CURS);
    k_fill<<<(EE + 255) / 256, 256, 0, stream>>>(dstp, CURS, EIDX);

    const int NSTRIP = (NN + 63) / 64;   // 1563

    // node init
    k_embed<<<(NN + 3) / 4, 256, 0, stream>>>(x, atom_emb, att_vec, AGG);
    k_smm<0, 0, 328><<<NSTRIP, 256, 0, stream>>>(
        AGG, DD, DD, OLWP, 384, out_lin_b, H, DD, DD, NN, 3);
    k_gaussg<<<NN, 320, 0, stream>>>(OFF, EIDX, edge_dist, g_means, g_stds,
                                     scale_p, H);

    float* P = H;
    float* Q = AGG;
    for (int l = 0; l < LL; l++) {
        const float* e0 = edge_emb + (size_t)((l * 3 + 0) * 5) * DD;
        const float* e1 = edge_emb + (size_t)((l * 3 + 1) * 5) * DD;
        const float* e2 = edge_emb + (size_t)((l * 3 + 2) * 5) * DD;
        k_agg<<<NN, 320, 0, stream>>>(P, OFF, EIDX, srcp, edge_attr,
                                      e0, e1, e2, SUM, SUMQ, l > 0 ? 1 : 0, Q);
        short* HID = (short*)P;
        // HID(bf16) = relu(Q @ W1 + b1)
        k_smm<0, 1, 328><<<NSTRIP, 256, 0, stream>>>(
            Q, DD, DD, W1P + (size_t)l * 10 * 640 * 32, 640,
            mlp_b1 + (size_t)l * D2, HID, D2, D2, NN, 5);
        // Q = HID @ W2 + b2 (fp32, BN deferred)
        k_smm<1, 0, 616><<<NSTRIP, 256, 0, stream>>>(
            HID, D2, D2, W2P + (size_t)l * 19 * 384 * 32, 384,
            mlp_b2 + (size_t)l * DD, Q, DD, DD, NN, 3);
        hipMemsetAsync(SUM, 0, DD * 4, stream);
        hipMemsetAsync(SUMQ, 0, DD * 4, stream);
        k_stats<<<(NN + ROWS_PER - 1) / ROWS_PER, 320, 0, stream>>>(Q, SUM, SUMQ);
        k_bnprep<<<2, 256, 0, stream>>>(SUM, SUMQ, bn_gamma + (size_t)l * DD,
                                        bn_beta + (size_t)l * DD);
        float* t2 = P; P = Q; Q = t2;
    }

    // pooling; last BN folded into k_hgdiv (affine after mean — exact)
    hipMemsetAsync(CNT, 0, (size_t)GG * 4, stream);
    hipMemsetAsync(HG, 0, (size_t)GG * DD * 4, stream);
    k_count<<<(NN + 255) / 256, 256, 0, stream>>>(batch, CNT);
    k_pool<<<(NN + ROWS_PER - 1) / ROWS_PER, 320, 0, stream>>>(P, batch, HG);
    k_hgdiv<<<(GG * DD + 255) / 256, 256, 0, stream>>>(HG, CNT, SUM, SUMQ);
    {
        dim3 grid((FEATN + 15) / 16, (GG + 15) / 16);
        k_gemm<<<grid, 256, 16 * DD * 4, stream>>>(HG, feat_w, feat_b, HFEAT, outp,
                                                   GG, DD, FEATN, 0);
    }
    {
        dim3 grid((FEATN + 15) / 16, (GG + 15) / 16);
        k_gemm<<<grid, 256, 16 * FEATN * 4, stream>>>(HFEAT, ol_w1, ol_b1, TMP, nullptr,
                                                      GG, FEATN, FEATN, 1);
    }
    {
        dim3 grid((OUT2 + 15) / 16, (GG + 15) / 16);
        k_gemm<<<grid, 256, 16 * FEATN * 4, stream>>>(TMP, ol_w2, ol_b2, nullptr,
                                                      outp + (size_t)GG * FEATN,
                                                      GG, FEATN, OUT2, 0);
    }
}

// Round 11
// 4586.731 us; speedup vs baseline: 1.0376x; 1.0376x over previous
//
#include <hip/hip_runtime.h>
#include <hip/hip_bf16.h>

// GINet forward, fp32 in/out. R11: zero-LDS direct-fragment MFMA GEMM (k_dmm)
// — A fragments straight from bf16 global rows (16B-aligned strides), B from
// L2-resident packed weights, no barriers, full TLP. Activations bf16 between
// agg->GEMM1 (stride 320, pad cols zeroed) and GEMM1->GEMM2 (stride 600).

#define NN   100000
#define EE   200000
#define GG   2000
#define DD   300
#define D2   600
#define LL   5
#define FEATN 512
#define OUT2 256
#define ROWS_PER 256

typedef __hip_bfloat16 bf16;
typedef short vec8s __attribute__((ext_vector_type(8)));
typedef float vec4f __attribute__((ext_vector_type(4)));

__device__ __forceinline__ short f2bs(float v) {
    bf16 h = __float2bfloat16(v);
    return __builtin_bit_cast(short, h);
}

// ---- weight prepack: src[K][N] fp32 -> dst[kt][col<NPAD][32] bf16 ----
__global__ void k_pack(const float* __restrict__ src, short* __restrict__ dst,
                       int Ksrc, int Nsrc, int KT, int NPAD)
{
    int idx = blockIdx.x * 256 + threadIdx.x;
    int total = KT * NPAD * 32;
    if (idx >= total) return;
    int col = idx % NPAD;
    int tmp = idx / NPAD;
    int kk  = tmp % 32;
    int kt  = tmp / 32;
    int k = kt * 32 + kk;
    short v = 0;
    if (k < Ksrc && col < Nsrc) v = f2bs(src[(size_t)k * Nsrc + col]);
    dst[((size_t)kt * NPAD + col) * 32 + kk] = v;
}

// ---- direct-fragment MFMA GEMM: no LDS, no barriers ----
// A: bf16 rows, stride lda shorts (row base must be 16B-aligned).
// Each block: 64 rows (wave wv -> rows rb+wv*16..+15), loops NCT 128-col tiles.
template<int OUT_BF_RELU, int KT>
__global__ __launch_bounds__(256) void k_dmm(
    const short* __restrict__ A, int lda,
    const short* __restrict__ WP, int npad,
    const float* __restrict__ bias,
    void* __restrict__ out, int ldo, int N, int M, int NCT)
{
    const int t = threadIdx.x;
    const int wv = t >> 6, lane = t & 63;
    const int m = lane & 15, quad = lane >> 4;
    const int rb = (int)blockIdx.x * 64;
    int ga = rb + wv * 16 + m;
    if (ga > M - 1) ga = M - 1;            // clamp; stores guarded separately
    const short* arow = A + (size_t)ga * lda + quad * 8;

    for (int ct = 0; ct < NCT; ct++) {
        const int cb = ct * 128;
        vec4f acc[8];
#pragma unroll
        for (int cf = 0; cf < 8; cf++) acc[cf] = (vec4f)0.f;

#pragma unroll
        for (int kt = 0; kt < KT; kt++) {
            vec8s af = *(const vec8s*)(arow + kt * 32);
            const short* wb = WP + ((size_t)kt * npad + cb + m) * 32 + quad * 8;
#pragma unroll
            for (int cf = 0; cf < 8; cf++) {
                vec8s bfr = *(const vec8s*)(wb + cf * 512);   // 16 cols x 32 k
                acc[cf] = __builtin_amdgcn_mfma_f32_16x16x32_bf16(af, bfr, acc[cf], 0, 0, 0);
            }
        }
        // epilogue: C/D col=lane&15, row=quad*4+reg (HW-validated)
        int grow0 = rb + wv * 16 + quad * 4;
#pragma unroll
        for (int cf = 0; cf < 8; cf++) {
            int gc = cb + cf * 16 + m;
            if (gc >= N) continue;
            float bv = bias[gc];
#pragma unroll
            for (int reg = 0; reg < 4; reg++) {
                int g = grow0 + reg;
                if (g < M) {
                    float v = acc[cf][reg] + bv;
                    if (OUT_BF_RELU)
                        ((short*)out)[(size_t)g * ldo + gc] = f2bs(fmaxf(v, 0.f));
                    else
                        ((float*)out)[(size_t)g * ldo + gc] = v;
                }
            }
        }
    }
}

// ============ CSR build ============
__global__ void k_degree(const int* __restrict__ dst, int* __restrict__ deg) {
    int e = blockIdx.x * 256 + threadIdx.x;
    if (e < EE) atomicAdd(&deg[dst[e]], 1);
}

__global__ void k_scan1(const int* __restrict__ deg, int* __restrict__ off,
                        int* __restrict__ bsum)
{
    __shared__ int s[256];
    int i = blockIdx.x * 256 + threadIdx.x;
    int v = (i < NN) ? deg[i] : 0;
    s[threadIdx.x] = v;
    __syncthreads();
    for (int o = 1; o < 256; o <<= 1) {
        int tv = (threadIdx.x >= o) ? s[threadIdx.x - o] : 0;
        __syncthreads();
        s[threadIdx.x] += tv;
        __syncthreads();
    }
    if (i < NN) off[i] = s[threadIdx.x] - v;
    if (threadIdx.x == 255) bsum[blockIdx.x] = s[255];
}

__global__ void k_scan2(int* __restrict__ bsum, int* __restrict__ off, int nb) {
    if (threadIdx.x != 0 || blockIdx.x != 0) return;
    int run = 0;
    for (int b = 0; b < nb; b++) { int t = bsum[b]; bsum[b] = run; run += t; }
    off[NN] = run;
}

__global__ void k_scan3(int* __restrict__ off, const int* __restrict__ bsum,
                        int* __restrict__ curs)
{
    int i = blockIdx.x * 256 + threadIdx.x;
    if (i >= NN) return;
    int v = off[i] + bsum[i >> 8];
    off[i] = v;
    curs[i] = v;
}

__global__ void k_fill(const int* __restrict__ dst, int* __restrict__ curs,
                       int* __restrict__ eidx)
{
    int e = blockIdx.x * 256 + threadIdx.x;
    if (e >= EE) return;
    int pos = atomicAdd(&curs[dst[e]], 1);
    eidx[pos] = e;
}

// ============ embed attention -> bf16 rows (stride 320, pad cols zeroed) ====
__global__ __launch_bounds__(256) void k_embed(
    const int* __restrict__ x, const float* __restrict__ atom_emb,
    const float* __restrict__ att_vec, short* __restrict__ fusedb)
{
    int wave = threadIdx.x >> 6;
    int lane = threadIdx.x & 63;
    int n = blockIdx.x * 4 + wave;
    if (n >= NN) return;

    float att[5];
#pragma unroll
    for (int j = 0; j < 5; j++) {
        int d = lane + 64 * j;
        att[j] = (d < DD) ? att_vec[d] : 0.f;
    }
    float emb[9][5];
    float sc[9];
#pragma unroll
    for (int f = 0; f < 9; f++) {
        int idx = x[n * 9 + f];
        const float* p = atom_emb + (size_t)(f * 119 + idx) * DD;
        float partial = 0.f;
#pragma unroll
        for (int j = 0; j < 5; j++) {
            int d = lane + 64 * j;
            float v = (d < DD) ? p[d] : 0.f;
            emb[f][j] = v;
            partial += v * att[j];
        }
#pragma unroll
        for (int off = 32; off; off >>= 1) partial += __shfl_xor(partial, off, 64);
        sc[f] = partial;
    }
    float mx = sc[0];
#pragma unroll
    for (int f = 1; f < 9; f++) mx = fmaxf(mx, sc[f]);
    float s = 0.f;
#pragma unroll
    for (int f = 0; f < 9; f++) { sc[f] = __expf(sc[f] - mx); s += sc[f]; }
    float inv = 1.f / s;
#pragma unroll
    for (int j = 0; j < 5; j++) {
        int d = lane + 64 * j;   // covers 0..319 exactly
        float acc = 0.f;
        if (d < DD) {
#pragma unroll
            for (int f = 0; f < 9; f++) acc += emb[f][j] * sc[f];
            acc *= inv;
        }
        fusedb[(size_t)n * 320 + d] = (d < DD) ? f2bs(acc) : (short)0;
    }
}

// ---- gaussian basis, CSR gather (adds into fp32 H) ----
__global__ __launch_bounds__(320) void k_gaussg(
    const int* __restrict__ off, const int* __restrict__ eidx,
    const float* __restrict__ dist, const float* __restrict__ g_means,
    const float* __restrict__ g_stds, const float* __restrict__ scale_p,
    float* __restrict__ H)
{
    int n = blockIdx.x;
    int d = threadIdx.x;
    if (d >= DD) return;
    int beg = off[n], end = off[n + 1];
    if (beg == end) return;
    float sd = fabsf(g_stds[d]) + 0.01f;
    float mean = g_means[d];
    float inv_asd = 1.f / (2.5066263f * sd);
    float sum = 0.f;
    for (int i = beg; i < end; i++) {
        float xv = dist[eidx[i]];
        float z = (xv - mean) / sd;
        sum += __expf(-0.5f * z * z) * inv_asd;
    }
    int deg = end - beg;
    int c = deg - 1; c = c < 0 ? 0 : (c > 3 ? 3 : c);
    H[(size_t)n * DD + d] += __expf(scale_p[c * DD + d]) * sum;
}

// ---- fused aggregation, folded BN+ReLU, bf16 output rows (stride 320) ----
__global__ __launch_bounds__(320) void k_agg(
    const float* __restrict__ P, const int* __restrict__ off,
    const int* __restrict__ eidx, const int* __restrict__ src,
    const int* __restrict__ attr,
    const float* __restrict__ e0, const float* __restrict__ e1,
    const float* __restrict__ e2,
    const float* __restrict__ scale, const float* __restrict__ shift,
    int apply, short* __restrict__ Qb)
{
    int n = blockIdx.x;
    int d = threadIdx.x;
    if (d >= DD) {                       // threads 300..319: zero the pad cols
        if (d < 320) Qb[(size_t)n * 320 + d] = 0;
        return;
    }
    float sc = apply ? scale[d] : 1.f;
    float sh = apply ? shift[d] : 0.f;
    float self = P[(size_t)n * DD + d];
    if (apply) self = fmaxf(self * sc + sh, 0.f);
    float acc = self + e0[4 * DD + d] + e1[d] + e2[d];
    int beg = off[n], end = off[n + 1];
    for (int i = beg; i < end; i++) {
        int e = eidx[i];
        int s = src[e];
        int a0 = attr[e * 3], a1 = attr[e * 3 + 1], a2 = attr[e * 3 + 2];
        float v = P[(size_t)s * DD + d];
        if (apply) v = fmaxf(v * sc + sh, 0.f);
        acc += v + e0[(size_t)a0 * DD + d] + e1[(size_t)a1 * DD + d]
                 + e2[(size_t)a2 * DD + d];
    }
    Qb[(size_t)n * 320 + d] = f2bs(acc);
}

// ============ BN ============
__global__ __launch_bounds__(320) void k_stats(const float* __restrict__ H,
                                               float* __restrict__ sum,
                                               float* __restrict__ sumsq)
{
    int d = threadIdx.x;
    if (d >= DD) return;
    int r0 = blockIdx.x * ROWS_PER;
    int rend = min(r0 + ROWS_PER, NN);
    float s = 0.f, sq = 0.f;
    for (int r = r0; r < rend; r++) {
        float v = H[(size_t)r * DD + d];
        s += v; sq += v * v;
    }
    atomicAdd(&sum[d], s);
    atomicAdd(&sumsq[d], sq);
}

__global__ void k_bnprep(float* __restrict__ sum, float* __restrict__ sumsq,
                         const float* __restrict__ gamma,
                         const float* __restrict__ beta)
{
    int d = threadIdx.x + blockIdx.x * 256;
    if (d >= DD) return;
    float mu = sum[d] * (1.f / NN);
    float var = sumsq[d] * (1.f / NN) - mu * mu;
    var = fmaxf(var, 0.f);
    float sc = gamma[d] * rsqrtf(var + 1e-5f);
    sum[d] = sc;
    sumsq[d] = beta[d] - mu * sc;
}

// ============ pooling + head ============
__global__ void k_count(const int* __restrict__ batch, float* __restrict__ cnt) {
    int n = blockIdx.x * 256 + threadIdx.x;
    if (n < NN) atomicAdd(&cnt[batch[n]], 1.0f);
}

__global__ __launch_bounds__(320) void k_pool(const float* __restrict__ H,
                                              const int* __restrict__ batch,
                                              float* __restrict__ HG)
{
    __shared__ int sb[ROWS_PER];
    int r0 = blockIdx.x * ROWS_PER;
    int rend = min(r0 + ROWS_PER, NN);
    for (int i = threadIdx.x; i < rend - r0; i += 320) sb[i] = batch[r0 + i];
    __syncthreads();
    int d = threadIdx.x;
    if (d >= DD) return;
    int cur = sb[0];
    float acc = 0.f;
    for (int r = r0; r < rend; r++) {
        int b = sb[r - r0];
        if (b != cur) { atomicAdd(&HG[(size_t)cur * DD + d], acc); acc = 0.f; cur = b; }
        acc += H[(size_t)r * DD + d];
    }
    atomicAdd(&HG[(size_t)cur * DD + d], acc);
}

__global__ void k_hgdiv(float* __restrict__ HG, const float* __restrict__ cnt,
                        const float* __restrict__ scale,
                        const float* __restrict__ shift)
{
    int idx = blockIdx.x * 256 + threadIdx.x;
    if (idx >= GG * DD) return;
    int d = idx % DD;
    float mean = HG[idx] / fmaxf(cnt[idx / DD], 1.0f);
    HG[idx] = mean * scale[d] + shift[d];
}

__global__ __launch_bounds__(256) void k_gemm(
    const float* __restrict__ A, const float* __restrict__ W,
    const float* __restrict__ bias, float* __restrict__ Cf,
    float* __restrict__ Cout, int M, int K, int Ncol, int relu)
{
    extern __shared__ float Ash[];
    int tx = threadIdx.x & 15;
    int ty = threadIdx.x >> 4;
    int rb = blockIdx.y * 16;
    int col = blockIdx.x * 16 + tx;

    for (int idx = threadIdx.x; idx < 16 * K; idx += 256) {
        int r = idx / K, k = idx - r * K;
        int row = rb + r;
        Ash[idx] = (row < M) ? A[(size_t)row * K + k] : 0.f;
    }
    __syncthreads();

    if (col < Ncol) {
        float acc = bias[col];
        const float* a = Ash + ty * K;
        const float* w = W + col;
        for (int k = 0; k < K; k++) acc += a[k] * w[(size_t)k * Ncol];
        if (relu) acc = fmaxf(acc, 0.f);
        int row = rb + ty;
        if (row < M) {
            if (Cf)   Cf[(size_t)row * Ncol + col] = acc;
            if (Cout) Cout[(size_t)row * Ncol + col] = acc;
        }
    }
}

extern "C" void kernel_launch(void* const* d_in, const int* in_sizes, int n_in,
                              void* d_out, int out_size, void* d_ws, size_t ws_size,
                              hipStream_t stream)
{
    const int*   x          = (const int*)  d_in[0];
    const int*   edge_index = (const int*)  d_in[1];
    const int*   edge_attr  = (const int*)  d_in[2];
    const float* edge_dist  = (const float*)d_in[3];
    const int*   batch      = (const int*)  d_in[4];
    const float* atom_emb   = (const float*)d_in[5];
    const float* att_vec    = (const float*)d_in[6];
    const float* out_lin_w  = (const float*)d_in[7];
    const float* out_lin_b  = (const float*)d_in[8];
    const float* g_means    = (const float*)d_in[9];
    const float* g_stds     = (const float*)d_in[10];
    const float* scale_p    = (const float*)d_in[11];
    const float* edge_emb   = (const float*)d_in[12];
    const float* mlp_w1     = (const float*)d_in[13];
    const float* mlp_b1     = (const float*)d_in[14];
    const float* mlp_w2     = (const float*)d_in[15];
    const float* mlp_b2     = (const float*)d_in[16];
    const float* bn_gamma   = (const float*)d_in[17];
    const float* bn_beta    = (const float*)d_in[18];
    const float* feat_w     = (const float*)d_in[19];
    const float* feat_b     = (const float*)d_in[20];
    const float* ol_w1      = (const float*)d_in[21];
    const float* ol_b1      = (const float*)d_in[22];
    const float* ol_w2      = (const float*)d_in[23];
    const float* ol_b2      = (const float*)d_in[24];
    (void)in_sizes; (void)n_in; (void)out_size; (void)ws_size;

    const int* srcp = edge_index;
    const int* dstp = edge_index + EE;

    char* ws = (char*)d_ws;
    size_t off_b = 0;
    auto alloc = [&](size_t bytes) -> char* {
        char* p = ws + off_b;
        off_b += (bytes + 255) & ~(size_t)255;
        return p;
    };
    // +256B tail pads: GEMM2's last-row fragment overshoot (16B) stays in-buffer
    float* H     = (float*)alloc((size_t)NN * DD * 4 + 256);
    float* AGG   = (float*)alloc((size_t)NN * DD * 4 + 256);
    int*   DEG   = (int*)  alloc((size_t)NN * 4);
    float* SUM   = (float*)alloc(DD * 4);
    float* SUMQ  = (float*)alloc(DD * 4);
    float* CNT   = (float*)alloc(GG * 4);
    float* HG    = (float*)alloc((size_t)GG * DD * 4);     // } pool 10,592,000 B
    float* HFEAT = (float*)alloc((size_t)GG * FEATN * 4);  // } packed W + CSR
    float* TMP   = (float*)alloc((size_t)GG * FEATN * 4);  // } during loop

    short* OLWP = (short*)HG;
    short* W1P  = OLWP + (size_t)10 * 384 * 32;
    short* W2P  = W1P + (size_t)LL * 10 * 640 * 32;
    char*  csr  = (char*)(W2P + (size_t)LL * 19 * 384 * 32);
    int*   OFF  = (int*)csr;
    int*   CURS = (int*)(csr + 400128);
    int*   EIDX = (int*)(csr + 800128);
    int*   BSUM = (int*)CNT;

    float* outp = (float*)d_out;

    // prepack weights
    k_pack<<<480, 256, 0, stream>>>(out_lin_w, OLWP, 300, 300, 10, 384);
    for (int l = 0; l < LL; l++) {
        k_pack<<<800, 256, 0, stream>>>(mlp_w1 + (size_t)l * DD * D2,
                                        W1P + (size_t)l * 10 * 640 * 32, DD, D2, 10, 640);
        k_pack<<<912, 256, 0, stream>>>(mlp_w2 + (size_t)l * D2 * DD,
                                        W2P + (size_t)l * 19 * 384 * 32, D2, DD, 19, 384);
    }

    // CSR build
    hipMemsetAsync(DEG, 0, (size_t)NN * 4, stream);
    k_degree<<<(EE + 255) / 256, 256, 0, stream>>>(dstp, DEG);
    k_scan1<<<391, 256, 0, stream>>>(DEG, OFF, BSUM);
    k_scan2<<<1, 64, 0, stream>>>(BSUM, OFF, 391);
    k_scan3<<<391, 256, 0, stream>>>(OFF, BSUM, CURS);
    k_fill<<<(EE + 255) / 256, 256, 0, stream>>>(dstp, CURS, EIDX);

    const int NSTRIP = (NN + 63) / 64;   // 1563

    // node init: embed(bf16) -> dmm -> gauss
    short* QB0 = (short*)AGG;
    k_embed<<<(NN + 3) / 4, 256, 0, stream>>>(x, atom_emb, att_vec, QB0);
    k_dmm<0, 10><<<NSTRIP, 256, 0, stream>>>(
        QB0, 320, OLWP, 384, out_lin_b, H, DD, DD, NN, 3);
    k_gaussg<<<NN, 320, 0, stream>>>(OFF, EIDX, edge_dist, g_means, g_stds,
                                     scale_p, H);

    float* P = H;
    float* Q = AGG;
    for (int l = 0; l < LL; l++) {
        const float* e0 = edge_emb + (size_t)((l * 3 + 0) * 5) * DD;
        const float* e1 = edge_emb + (size_t)((l * 3 + 1) * 5) * DD;
        const float* e2 = edge_emb + (size_t)((l * 3 + 2) * 5) * DD;
        short* Qb  = (short*)Q;
        short* HID = (short*)P;
        // agg: bf16 rows (stride 320, pads zeroed), folded BN+ReLU of prev layer
        k_agg<<<NN, 320, 0, stream>>>(P, OFF, EIDX, srcp, edge_attr,
                                      e0, e1, e2, SUM, SUMQ, l > 0 ? 1 : 0, Qb);
        // GEMM1: HID(bf16, stride 600) = relu(Qb @ W1 + b1)
        k_dmm<1, 10><<<NSTRIP, 256, 0, stream>>>(
            Qb, 320, W1P + (size_t)l * 10 * 640 * 32, 640,
            mlp_b1 + (size_t)l * D2, HID, D2, D2, NN, 5);
        // GEMM2: Q(fp32) = HID @ W2 + b2 (BN deferred via bnprep fold)
        k_dmm<0, 19><<<NSTRIP, 256, 0, stream>>>(
            HID, D2, W2P + (size_t)l * 19 * 384 * 32, 384,
            mlp_b2 + (size_t)l * DD, Q, DD, DD, NN, 3);
        hipMemsetAsync(SUM, 0, DD * 4, stream);
        hipMemsetAsync(SUMQ, 0, DD * 4, stream);
        k_stats<<<(NN + ROWS_PER - 1) / ROWS_PER, 320, 0, stream>>>(Q, SUM, SUMQ);
        k_bnprep<<<2, 256, 0, stream>>>(SUM, SUMQ, bn_gamma + (size_t)l * DD,
                                        bn_beta + (size_t)l * DD);
        float* t2 = P; P = Q; Q = t2;
    }

    // pooling; last BN folded into k_hgdiv
    hipMemsetAsync(CNT, 0, (size_t)GG * 4, stream);
    hipMemsetAsync(HG, 0, (size_t)GG * DD * 4, stream);
    k_count<<<(NN + 255) / 256, 256, 0, stream>>>(batch, CNT);
    k_pool<<<(NN + ROWS_PER - 1) / ROWS_PER, 320, 0, stream>>>(P, batch, HG);
    k_hgdiv<<<(GG * DD + 255) / 256, 256, 0, stream>>>(HG, CNT, SUM, SUMQ);
    {
        dim3 grid((FEATN + 15) / 16, (GG + 15) / 16);
        k_gemm<<<grid, 256, 16 * DD * 4, stream>>>(HG, feat_w, feat_b, HFEAT, outp,
                                                   GG, DD, FEATN, 0);
    }
    {
        dim3 grid((FEATN + 15) / 16, (GG + 15) / 16);
        k_gemm<<<grid, 256, 16 * FEATN * 4, stream>>>(HFEAT, ol_w1, ol_b1, TMP, nullptr,
                                                      GG, FEATN, FEATN, 1);
    }
    {
        dim3 grid((OUT2 + 15) / 16, (GG + 15) / 16);
        k_gemm<<<grid, 256, 16 * FEATN * 4, stream>>>(TMP, ol_w2, ol_b2, nullptr,
                                                      outp + (size_t)GG * FEATN,
                                                      GG, FEATN, OUT2, 0);
    }
}

// Round 12
// 3403.772 us; speedup vs baseline: 1.3983x; 1.3475x over previous
//
#include <hip/hip_runtime.h>
#include <hip/hip_bf16.h>

// GINet forward, fp32 in/out. R12: fused per-layer MLP (k_mlp2) — stage1
// relu(Qb@W1+b1) -> LDS (bf16, stride 648: conflict-free), stage2 LDS@W2+b2
// -> P fp32. Kills the 240MB/layer HID round-trip and one dispatch/layer.
// 32-row strips share B fragments across two row groups (halves B L2 traffic).

#define NN   100000
#define EE   200000
#define GG   2000
#define DD   300
#define D2   600
#define LL   5
#define FEATN 512
#define OUT2 256
#define ROWS_PER 256

typedef __hip_bfloat16 bf16;
typedef short vec8s __attribute__((ext_vector_type(8)));
typedef float vec4f __attribute__((ext_vector_type(4)));

__device__ __forceinline__ short f2bs(float v) {
    bf16 h = __float2bfloat16(v);
    return __builtin_bit_cast(short, h);
}

// ---- weight prepack: src[K][N] fp32 -> dst[kt][col<NPAD][32] bf16 ----
__global__ void k_pack(const float* __restrict__ src, short* __restrict__ dst,
                       int Ksrc, int Nsrc, int KT, int NPAD)
{
    int idx = blockIdx.x * 256 + threadIdx.x;
    int total = KT * NPAD * 32;
    if (idx >= total) return;
    int col = idx % NPAD;
    int tmp = idx / NPAD;
    int kk  = tmp % 32;
    int kt  = tmp / 32;
    int k = kt * 32 + kk;
    short v = 0;
    if (k < Ksrc && col < Nsrc) v = f2bs(src[(size_t)k * Nsrc + col]);
    dst[((size_t)kt * NPAD + col) * 32 + kk] = v;
}

// ---- fused MLP layer: P = (Qb @ W1 + b1).relu() @ W2 + b2 ----
// Block = 32 rows. Stage1 cols split 4 waves x 160; HID in LDS bf16.
__global__ __launch_bounds__(256) void k_mlp2(
    const short* __restrict__ Qb,          // [NN][320] bf16, pads zeroed
    const short* __restrict__ W1P,         // [10][640][32] bf16 packed
    const float* __restrict__ b1,          // [600]
    const short* __restrict__ W2P,         // [19][384][32] bf16 packed
    const float* __restrict__ b2,          // [300]
    float* __restrict__ Pout)              // [NN][300] fp32
{
    __shared__ __align__(16) short Hl[32][648];   // 41,472 B
    const int t = threadIdx.x;
    const int wv = t >> 6, lane = t & 63;
    const int m = lane & 15, quad = lane >> 4;
    const int rb = (int)blockIdx.x * 32;

    // zero k-pad cols 600..647 (stage2 kt=18 reads up to 607)
    for (int i = t; i < 32 * 48; i += 256) {
        int r = i / 48, c = 600 + (i - r * 48);
        Hl[r][c] = 0;
    }

    // ---- stage 1: HID[32][600] = relu(Qb[rb:rb+32] @ W1 + b1) ----
    {
        const short* arow0 = Qb + (size_t)(rb + m) * 320 + quad * 8;
        const short* arow1 = arow0 + (size_t)16 * 320;
        vec4f acc[2][10];
#pragma unroll
        for (int g = 0; g < 2; g++)
#pragma unroll
            for (int cf = 0; cf < 10; cf++) acc[g][cf] = (vec4f)0.f;

        for (int kt = 0; kt < 10; kt++) {
            vec8s af0 = *(const vec8s*)(arow0 + kt * 32);
            vec8s af1 = *(const vec8s*)(arow1 + kt * 32);
            const short* wb = W1P + ((size_t)kt * 640 + wv * 160 + m) * 32 + quad * 8;
#pragma unroll
            for (int cf = 0; cf < 10; cf++) {
                vec8s bfr = *(const vec8s*)(wb + cf * 512);
                acc[0][cf] = __builtin_amdgcn_mfma_f32_16x16x32_bf16(af0, bfr, acc[0][cf], 0, 0, 0);
                acc[1][cf] = __builtin_amdgcn_mfma_f32_16x16x32_bf16(af1, bfr, acc[1][cf], 0, 0, 0);
            }
        }
        // epilogue -> LDS (C/D: col=lane&15, row=quad*4+reg; HW-validated)
#pragma unroll
        for (int cf = 0; cf < 10; cf++) {
            int col = wv * 160 + cf * 16 + m;
            float bv = (col < D2) ? b1[col] : 0.f;
            if (col < D2) {
#pragma unroll
                for (int g = 0; g < 2; g++)
#pragma unroll
                    for (int reg = 0; reg < 4; reg++) {
                        float v = acc[g][cf][reg] + bv;
                        Hl[g * 16 + quad * 4 + reg][col] = f2bs(fmaxf(v, 0.f));
                    }
            }
        }
    }
    __syncthreads();

    // ---- stage 2: Pout[rb:rb+32] = HID @ W2 + b2 ----
    {
        vec4f acc[2][6];
#pragma unroll
        for (int g = 0; g < 2; g++)
#pragma unroll
            for (int cf = 0; cf < 6; cf++) acc[g][cf] = (vec4f)0.f;

        for (int kt = 0; kt < 19; kt++) {
            vec8s af0 = *(const vec8s*)&Hl[m][kt * 32 + quad * 8];
            vec8s af1 = *(const vec8s*)&Hl[16 + m][kt * 32 + quad * 8];
            const short* wb = W2P + ((size_t)kt * 384 + wv * 96 + m) * 32 + quad * 8;
#pragma unroll
            for (int cf = 0; cf < 6; cf++) {
                vec8s bfr = *(const vec8s*)(wb + cf * 512);
                acc[0][cf] = __builtin_amdgcn_mfma_f32_16x16x32_bf16(af0, bfr, acc[0][cf], 0, 0, 0);
                acc[1][cf] = __builtin_amdgcn_mfma_f32_16x16x32_bf16(af1, bfr, acc[1][cf], 0, 0, 0);
            }
        }
#pragma unroll
        for (int cf = 0; cf < 6; cf++) {
            int gc = wv * 96 + cf * 16 + m;
            if (gc >= DD) continue;
            float bv = b2[gc];
#pragma unroll
            for (int g = 0; g < 2; g++)
#pragma unroll
                for (int reg = 0; reg < 4; reg++) {
                    int grow = rb + g * 16 + quad * 4 + reg;
                    Pout[(size_t)grow * DD + gc] = acc[g][cf][reg] + bv;
                }
        }
    }
}

// ---- direct-fragment MFMA GEMM (embed GEMM only) ----
template<int OUT_BF_RELU, int KT>
__global__ __launch_bounds__(256) void k_dmm(
    const short* __restrict__ A, int lda,
    const short* __restrict__ WP, int npad,
    const float* __restrict__ bias,
    void* __restrict__ out, int ldo, int N, int M, int NCT)
{
    const int t = threadIdx.x;
    const int wv = t >> 6, lane = t & 63;
    const int m = lane & 15, quad = lane >> 4;
    const int rb = (int)blockIdx.x * 64;
    int ga = rb + wv * 16 + m;
    if (ga > M - 1) ga = M - 1;
    const short* arow = A + (size_t)ga * lda + quad * 8;

    for (int ct = 0; ct < NCT; ct++) {
        const int cb = ct * 128;
        vec4f acc[8];
#pragma unroll
        for (int cf = 0; cf < 8; cf++) acc[cf] = (vec4f)0.f;

#pragma unroll
        for (int kt = 0; kt < KT; kt++) {
            vec8s af = *(const vec8s*)(arow + kt * 32);
            const short* wb = WP + ((size_t)kt * npad + cb + m) * 32 + quad * 8;
#pragma unroll
            for (int cf = 0; cf < 8; cf++) {
                vec8s bfr = *(const vec8s*)(wb + cf * 512);
                acc[cf] = __builtin_amdgcn_mfma_f32_16x16x32_bf16(af, bfr, acc[cf], 0, 0, 0);
            }
        }
        int grow0 = rb + wv * 16 + quad * 4;
#pragma unroll
        for (int cf = 0; cf < 8; cf++) {
            int gc = cb + cf * 16 + m;
            if (gc >= N) continue;
            float bv = bias[gc];
#pragma unroll
            for (int reg = 0; reg < 4; reg++) {
                int g = grow0 + reg;
                if (g < M) {
                    float v = acc[cf][reg] + bv;
                    if (OUT_BF_RELU)
                        ((short*)out)[(size_t)g * ldo + gc] = f2bs(fmaxf(v, 0.f));
                    else
                        ((float*)out)[(size_t)g * ldo + gc] = v;
                }
            }
        }
    }
}

// ============ CSR build ============
__global__ void k_degree(const int* __restrict__ dst, int* __restrict__ deg) {
    int e = blockIdx.x * 256 + threadIdx.x;
    if (e < EE) atomicAdd(&deg[dst[e]], 1);
}

__global__ void k_scan1(const int* __restrict__ deg, int* __restrict__ off,
                        int* __restrict__ bsum)
{
    __shared__ int s[256];
    int i = blockIdx.x * 256 + threadIdx.x;
    int v = (i < NN) ? deg[i] : 0;
    s[threadIdx.x] = v;
    __syncthreads();
    for (int o = 1; o < 256; o <<= 1) {
        int tv = (threadIdx.x >= o) ? s[threadIdx.x - o] : 0;
        __syncthreads();
        s[threadIdx.x] += tv;
        __syncthreads();
    }
    if (i < NN) off[i] = s[threadIdx.x] - v;
    if (threadIdx.x == 255) bsum[blockIdx.x] = s[255];
}

__global__ void k_scan2(int* __restrict__ bsum, int* __restrict__ off, int nb) {
    if (threadIdx.x != 0 || blockIdx.x != 0) return;
    int run = 0;
    for (int b = 0; b < nb; b++) { int t = bsum[b]; bsum[b] = run; run += t; }
    off[NN] = run;
}

__global__ void k_scan3(int* __restrict__ off, const int* __restrict__ bsum,
                        int* __restrict__ curs)
{
    int i = blockIdx.x * 256 + threadIdx.x;
    if (i >= NN) return;
    int v = off[i] + bsum[i >> 8];
    off[i] = v;
    curs[i] = v;
}

__global__ void k_fill(const int* __restrict__ dst, int* __restrict__ curs,
                       int* __restrict__ eidx)
{
    int e = blockIdx.x * 256 + threadIdx.x;
    if (e >= EE) return;
    int pos = atomicAdd(&curs[dst[e]], 1);
    eidx[pos] = e;
}

// ============ embed attention -> bf16 rows (stride 320, pads zeroed) ============
__global__ __launch_bounds__(256) void k_embed(
    const int* __restrict__ x, const float* __restrict__ atom_emb,
    const float* __restrict__ att_vec, short* __restrict__ fusedb)
{
    int wave = threadIdx.x >> 6;
    int lane = threadIdx.x & 63;
    int n = blockIdx.x * 4 + wave;
    if (n >= NN) return;

    float att[5];
#pragma unroll
    for (int j = 0; j < 5; j++) {
        int d = lane + 64 * j;
        att[j] = (d < DD) ? att_vec[d] : 0.f;
    }
    float emb[9][5];
    float sc[9];
#pragma unroll
    for (int f = 0; f < 9; f++) {
        int idx = x[n * 9 + f];
        const float* p = atom_emb + (size_t)(f * 119 + idx) * DD;
        float partial = 0.f;
#pragma unroll
        for (int j = 0; j < 5; j++) {
            int d = lane + 64 * j;
            float v = (d < DD) ? p[d] : 0.f;
            emb[f][j] = v;
            partial += v * att[j];
        }
#pragma unroll
        for (int off = 32; off; off >>= 1) partial += __shfl_xor(partial, off, 64);
        sc[f] = partial;
    }
    float mx = sc[0];
#pragma unroll
    for (int f = 1; f < 9; f++) mx = fmaxf(mx, sc[f]);
    float s = 0.f;
#pragma unroll
    for (int f = 0; f < 9; f++) { sc[f] = __expf(sc[f] - mx); s += sc[f]; }
    float inv = 1.f / s;
#pragma unroll
    for (int j = 0; j < 5; j++) {
        int d = lane + 64 * j;
        float acc = 0.f;
        if (d < DD) {
#pragma unroll
            for (int f = 0; f < 9; f++) acc += emb[f][j] * sc[f];
            acc *= inv;
        }
        fusedb[(size_t)n * 320 + d] = (d < DD) ? f2bs(acc) : (short)0;
    }
}

// ---- gaussian basis, CSR gather ----
__global__ __launch_bounds__(320) void k_gaussg(
    const int* __restrict__ off, const int* __restrict__ eidx,
    const float* __restrict__ dist, const float* __restrict__ g_means,
    const float* __restrict__ g_stds, const float* __restrict__ scale_p,
    float* __restrict__ H)
{
    int n = blockIdx.x;
    int d = threadIdx.x;
    if (d >= DD) return;
    int beg = off[n], end = off[n + 1];
    if (beg == end) return;
    float sd = fabsf(g_stds[d]) + 0.01f;
    float mean = g_means[d];
    float inv_asd = 1.f / (2.5066263f * sd);
    float sum = 0.f;
    for (int i = beg; i < end; i++) {
        float xv = dist[eidx[i]];
        float z = (xv - mean) / sd;
        sum += __expf(-0.5f * z * z) * inv_asd;
    }
    int deg = end - beg;
    int c = deg - 1; c = c < 0 ? 0 : (c > 3 ? 3 : c);
    H[(size_t)n * DD + d] += __expf(scale_p[c * DD + d]) * sum;
}

// ---- fused aggregation, folded BN+ReLU, bf16 output rows (stride 320) ----
__global__ __launch_bounds__(320) void k_agg(
    const float* __restrict__ P, const int* __restrict__ off,
    const int* __restrict__ eidx, const int* __restrict__ src,
    const int* __restrict__ attr,
    const float* __restrict__ e0, const float* __restrict__ e1,
    const float* __restrict__ e2,
    const float* __restrict__ scale, const float* __restrict__ shift,
    int apply, short* __restrict__ Qb)
{
    int n = blockIdx.x;
    int d = threadIdx.x;
    if (d >= DD) {
        if (d < 320) Qb[(size_t)n * 320 + d] = 0;
        return;
    }
    float sc = apply ? scale[d] : 1.f;
    float sh = apply ? shift[d] : 0.f;
    float self = P[(size_t)n * DD + d];
    if (apply) self = fmaxf(self * sc + sh, 0.f);
    float acc = self + e0[4 * DD + d] + e1[d] + e2[d];
    int beg = off[n], end = off[n + 1];
    for (int i = beg; i < end; i++) {
        int e = eidx[i];
        int s = src[e];
        int a0 = attr[e * 3], a1 = attr[e * 3 + 1], a2 = attr[e * 3 + 2];
        float v = P[(size_t)s * DD + d];
        if (apply) v = fmaxf(v * sc + sh, 0.f);
        acc += v + e0[(size_t)a0 * DD + d] + e1[(size_t)a1 * DD + d]
                 + e2[(size_t)a2 * DD + d];
    }
    Qb[(size_t)n * 320 + d] = f2bs(acc);
}

// ============ BN ============
__global__ __launch_bounds__(320) void k_stats(const float* __restrict__ H,
                                               float* __restrict__ sum,
                                               float* __restrict__ sumsq)
{
    int d = threadIdx.x;
    if (d >= DD) return;
    int r0 = blockIdx.x * ROWS_PER;
    int rend = min(r0 + ROWS_PER, NN);
    float s = 0.f, sq = 0.f;
    for (int r = r0; r < rend; r++) {
        float v = H[(size_t)r * DD + d];
        s += v; sq += v * v;
    }
    atomicAdd(&sum[d], s);
    atomicAdd(&sumsq[d], sq);
}

__global__ void k_bnprep(float* __restrict__ sum, float* __restrict__ sumsq,
                         const float* __restrict__ gamma,
                         const float* __restrict__ beta)
{
    int d = threadIdx.x + blockIdx.x * 256;
    if (d >= DD) return;
    float mu = sum[d] * (1.f / NN);
    float var = sumsq[d] * (1.f / NN) - mu * mu;
    var = fmaxf(var, 0.f);
    float sc = gamma[d] * rsqrtf(var + 1e-5f);
    sum[d] = sc;
    sumsq[d] = beta[d] - mu * sc;
}

// ============ pooling + head ============
__global__ void k_count(const int* __restrict__ batch, float* __restrict__ cnt) {
    int n = blockIdx.x * 256 + threadIdx.x;
    if (n < NN) atomicAdd(&cnt[batch[n]], 1.0f);
}

__global__ __launch_bounds__(320) void k_pool(const float* __restrict__ H,
                                              const int* __restrict__ batch,
                                              float* __restrict__ HG)
{
    __shared__ int sb[ROWS_PER];
    int r0 = blockIdx.x * ROWS_PER;
    int rend = min(r0 + ROWS_PER, NN);
    for (int i = threadIdx.x; i < rend - r0; i += 320) sb[i] = batch[r0 + i];
    __syncthreads();
    int d = threadIdx.x;
    if (d >= DD) return;
    int cur = sb[0];
    float acc = 0.f;
    for (int r = r0; r < rend; r++) {
        int b = sb[r - r0];
        if (b != cur) { atomicAdd(&HG[(size_t)cur * DD + d], acc); acc = 0.f; cur = b; }
        acc += H[(size_t)r * DD + d];
    }
    atomicAdd(&HG[(size_t)cur * DD + d], acc);
}

__global__ void k_hgdiv(float* __restrict__ HG, const float* __restrict__ cnt,
                        const float* __restrict__ scale,
                        const float* __restrict__ shift)
{
    int idx = blockIdx.x * 256 + threadIdx.x;
    if (idx >= GG * DD) return;
    int d = idx % DD;
    float mean = HG[idx] / fmaxf(cnt[idx / DD], 1.0f);
    HG[idx] = mean * scale[d] + shift[d];
}

__global__ __launch_bounds__(256) void k_gemm(
    const float* __restrict__ A, const float* __restrict__ W,
    const float* __restrict__ bias, float* __restrict__ Cf,
    float* __restrict__ Cout, int M, int K, int Ncol, int relu)
{
    extern __shared__ float Ash[];
    int tx = threadIdx.x & 15;
    int ty = threadIdx.x >> 4;
    int rb = blockIdx.y * 16;
    int col = blockIdx.x * 16 + tx;

    for (int idx = threadIdx.x; idx < 16 * K; idx += 256) {
        int r = idx / K, k = idx - r * K;
        int row = rb + r;
        Ash[idx] = (row < M) ? A[(size_t)row * K + k] : 0.f;
    }
    __syncthreads();

    if (col < Ncol) {
        float acc = bias[col];
        const float* a = Ash + ty * K;
        const float* w = W + col;
        for (int k = 0; k < K; k++) acc += a[k] * w[(size_t)k * Ncol];
        if (relu) acc = fmaxf(acc, 0.f);
        int row = rb + ty;
        if (row < M) {
            if (Cf)   Cf[(size_t)row * Ncol + col] = acc;
            if (Cout) Cout[(size_t)row * Ncol + col] = acc;
        }
    }
}

extern "C" void kernel_launch(void* const* d_in, const int* in_sizes, int n_in,
                              void* d_out, int out_size, void* d_ws, size_t ws_size,
                              hipStream_t stream)
{
    const int*   x          = (const int*)  d_in[0];
    const int*   edge_index = (const int*)  d_in[1];
    const int*   edge_attr  = (const int*)  d_in[2];
    const float* edge_dist  = (const float*)d_in[3];
    const int*   batch      = (const int*)  d_in[4];
    const float* atom_emb   = (const float*)d_in[5];
    const float* att_vec    = (const float*)d_in[6];
    const float* out_lin_w  = (const float*)d_in[7];
    const float* out_lin_b  = (const float*)d_in[8];
    const float* g_means    = (const float*)d_in[9];
    const float* g_stds     = (const float*)d_in[10];
    const float* scale_p    = (const float*)d_in[11];
    const float* edge_emb   = (const float*)d_in[12];
    const float* mlp_w1     = (const float*)d_in[13];
    const float* mlp_b1     = (const float*)d_in[14];
    const float* mlp_w2     = (const float*)d_in[15];
    const float* mlp_b2     = (const float*)d_in[16];
    const float* bn_gamma   = (const float*)d_in[17];
    const float* bn_beta    = (const float*)d_in[18];
    const float* feat_w     = (const float*)d_in[19];
    const float* feat_b     = (const float*)d_in[20];
    const float* ol_w1      = (const float*)d_in[21];
    const float* ol_b1      = (const float*)d_in[22];
    const float* ol_w2      = (const float*)d_in[23];
    const float* ol_b2      = (const float*)d_in[24];
    (void)in_sizes; (void)n_in; (void)out_size; (void)ws_size;

    const int* srcp = edge_index;
    const int* dstp = edge_index + EE;

    char* ws = (char*)d_ws;
    size_t off_b = 0;
    auto alloc = [&](size_t bytes) -> char* {
        char* p = ws + off_b;
        off_b += (bytes + 255) & ~(size_t)255;
        return p;
    };
    float* H     = (float*)alloc((size_t)NN * DD * 4 + 256);   // features (P)
    float* AGG   = (float*)alloc((size_t)NN * DD * 4 + 256);   // Qb bf16 rows
    int*   DEG   = (int*)  alloc((size_t)NN * 4);
    float* SUM   = (float*)alloc(DD * 4);
    float* SUMQ  = (float*)alloc(DD * 4);
    float* CNT   = (float*)alloc(GG * 4);
    float* HG    = (float*)alloc((size_t)GG * DD * 4);     // } pool 10,592,000 B
    float* HFEAT = (float*)alloc((size_t)GG * FEATN * 4);  // } packed W + CSR
    float* TMP   = (float*)alloc((size_t)GG * FEATN * 4);  // } during loop

    short* OLWP = (short*)HG;
    short* W1P  = OLWP + (size_t)10 * 384 * 32;
    short* W2P  = W1P + (size_t)LL * 10 * 640 * 32;
    char*  csr  = (char*)(W2P + (size_t)LL * 19 * 384 * 32);
    int*   OFF  = (int*)csr;
    int*   CURS = (int*)(csr + 400128);
    int*   EIDX = (int*)(csr + 800128);
    int*   BSUM = (int*)CNT;

    float* outp = (float*)d_out;

    // prepack weights
    k_pack<<<480, 256, 0, stream>>>(out_lin_w, OLWP, 300, 300, 10, 384);
    for (int l = 0; l < LL; l++) {
        k_pack<<<800, 256, 0, stream>>>(mlp_w1 + (size_t)l * DD * D2,
                                        W1P + (size_t)l * 10 * 640 * 32, DD, D2, 10, 640);
        k_pack<<<912, 256, 0, stream>>>(mlp_w2 + (size_t)l * D2 * DD,
                                        W2P + (size_t)l * 19 * 384 * 32, D2, DD, 19, 384);
    }

    // CSR build
    hipMemsetAsync(DEG, 0, (size_t)NN * 4, stream);
    k_degree<<<(EE + 255) / 256, 256, 0, stream>>>(dstp, DEG);
    k_scan1<<<391, 256, 0, stream>>>(DEG, OFF, BSUM);
    k_scan2<<<1, 64, 0, stream>>>(BSUM, OFF, 391);
    k_scan3<<<391, 256, 0, stream>>>(OFF, BSUM, CURS);
    k_fill<<<(EE + 255) / 256, 256, 0, stream>>>(dstp, CURS, EIDX);

    // node init: embed(bf16) -> dmm -> gauss
    short* QB = (short*)AGG;
    k_embed<<<(NN + 3) / 4, 256, 0, stream>>>(x, atom_emb, att_vec, QB);
    k_dmm<0, 10><<<(NN + 63) / 64, 256, 0, stream>>>(
        QB, 320, OLWP, 384, out_lin_b, H, DD, DD, NN, 3);
    k_gaussg<<<NN, 320, 0, stream>>>(OFF, EIDX, edge_dist, g_means, g_stds,
                                     scale_p, H);

    // layer loop: features stay in H; Qb staging in AGG
    for (int l = 0; l < LL; l++) {
        const float* e0 = edge_emb + (size_t)((l * 3 + 0) * 5) * DD;
        const float* e1 = edge_emb + (size_t)((l * 3 + 1) * 5) * DD;
        const float* e2 = edge_emb + (size_t)((l * 3 + 2) * 5) * DD;
        k_agg<<<NN, 320, 0, stream>>>(H, OFF, EIDX, srcp, edge_attr,
                                      e0, e1, e2, SUM, SUMQ, l > 0 ? 1 : 0, QB);
        k_mlp2<<<NN / 32, 256, 0, stream>>>(
            QB, W1P + (size_t)l * 10 * 640 * 32, mlp_b1 + (size_t)l * D2,
            W2P + (size_t)l * 19 * 384 * 32, mlp_b2 + (size_t)l * DD, H);
        hipMemsetAsync(SUM, 0, DD * 4, stream);
        hipMemsetAsync(SUMQ, 0, DD * 4, stream);
        k_stats<<<(NN + ROWS_PER - 1) / ROWS_PER, 320, 0, stream>>>(H, SUM, SUMQ);
        k_bnprep<<<2, 256, 0, stream>>>(SUM, SUMQ, bn_gamma + (size_t)l * DD,
                                        bn_beta + (size_t)l * DD);
    }

    // pooling; last BN folded into k_hgdiv
    hipMemsetAsync(CNT, 0, (size_t)GG * 4, stream);
    hipMemsetAsync(HG, 0, (size_t)GG * DD * 4, stream);
    k_count<<<(NN + 255) / 256, 256, 0, stream>>>(batch, CNT);
    k_pool<<<(NN + ROWS_PER - 1) / ROWS_PER, 320, 0, stream>>>(H, batch, HG);
    k_hgdiv<<<(GG * DD + 255) / 256, 256, 0, stream>>>(HG, CNT, SUM, SUMQ);
    {
        dim3 grid((FEATN + 15) / 16, (GG + 15) / 16);
        k_gemm<<<grid, 256, 16 * DD * 4, stream>>>(HG, feat_w, feat_b, HFEAT, outp,
                                                   GG, DD, FEATN, 0);
    }
    {
        dim3 grid((FEATN + 15) / 16, (GG + 15) / 16);
        k_gemm<<<grid, 256, 16 * FEATN * 4, stream>>>(HFEAT, ol_w1, ol_b1, TMP, nullptr,
                                                      GG, FEATN, FEATN, 1);
    }
    {
        dim3 grid((OUT2 + 15) / 16, (GG + 15) / 16);
        k_gemm<<<grid, 256, 16 * FEATN * 4, stream>>>(TMP, ol_w2, ol_b2, nullptr,
                                                      outp + (size_t)GG * FEATN,
                                                      GG, FEATN, OUT2, 0);
    }
}

// Round 13
// 3209.536 us; speedup vs baseline: 1.4829x; 1.0605x over previous
//
#include <hip/hip_runtime.h>
#include <hip/hip_bf16.h>

// GINet forward, fp32 in/out. R13: (1) BN stats fused into k_mlp2 epilogue
// (shfl-reduce over quad + 1 atomic pair per block-column) — k_stats deleted;
// (2) k_agg edge loads 6->2 via per-layer combined E[25][300] tables + packed
// EIDX = src|(combo<<17); (3) single SUM/SUMQ buffer, one memset per layer.

#define NN   100000
#define EE   200000
#define GG   2000
#define DD   300
#define D2   600
#define LL   5
#define FEATN 512
#define OUT2 256
#define ROWS_PER 256

typedef __hip_bfloat16 bf16;
typedef short vec8s __attribute__((ext_vector_type(8)));
typedef float vec4f __attribute__((ext_vector_type(4)));

__device__ __forceinline__ short f2bs(float v) {
    bf16 h = __float2bfloat16(v);
    return __builtin_bit_cast(short, h);
}

// ---- weight prepack: src[K][N] fp32 -> dst[kt][col<NPAD][32] bf16 ----
__global__ void k_pack(const float* __restrict__ src, short* __restrict__ dst,
                       int Ksrc, int Nsrc, int KT, int NPAD)
{
    int idx = blockIdx.x * 256 + threadIdx.x;
    int total = KT * NPAD * 32;
    if (idx >= total) return;
    int col = idx % NPAD;
    int tmp = idx / NPAD;
    int kk  = tmp % 32;
    int kt  = tmp / 32;
    int k = kt * 32 + kk;
    short v = 0;
    if (k < Ksrc && col < Nsrc) v = f2bs(src[(size_t)k * Nsrc + col]);
    dst[((size_t)kt * NPAD + col) * 32 + kk] = v;
}

// ---- combined edge-emb tables: E[l][c][d], c<24 = a0*6+a1*2+a2, c==24 self ----
__global__ void k_etab(const float* __restrict__ edge_emb, float* __restrict__ E)
{
    int i = blockIdx.x * 256 + threadIdx.x;
    if (i >= LL * 25 * DD) return;
    int d = i % DD;
    int t = i / DD;
    int c = t % 25;
    int l = t / 25;
    int a0 = (c == 24) ? 4 : (c / 6);
    int a1 = (c == 24) ? 0 : ((c % 6) / 2);
    int a2 = (c == 24) ? 0 : (c % 2);
    const float* e0 = edge_emb + (size_t)((l * 3 + 0) * 5) * DD;
    const float* e1 = edge_emb + (size_t)((l * 3 + 1) * 5) * DD;
    const float* e2 = edge_emb + (size_t)((l * 3 + 2) * 5) * DD;
    E[i] = e0[a0 * DD + d] + e1[a1 * DD + d] + e2[a2 * DD + d];
}

// ---- repack EIDX: edge id -> src | (combo<<17)  (src<2^17) ----
__global__ void k_repack(int* __restrict__ eidx, const int* __restrict__ src,
                         const int* __restrict__ attr)
{
    int i = blockIdx.x * 256 + threadIdx.x;
    if (i >= EE) return;
    int e = eidx[i];
    int c = attr[e * 3] * 6 + attr[e * 3 + 1] * 2 + attr[e * 3 + 2];
    eidx[i] = src[e] | (c << 17);
}

// ---- fused MLP layer + BN stats: P = (Qb@W1+b1).relu()@W2+b2; SUM/SUMQ += ----
__global__ __launch_bounds__(256) void k_mlp2(
    const short* __restrict__ Qb, const short* __restrict__ W1P,
    const float* __restrict__ b1, const short* __restrict__ W2P,
    const float* __restrict__ b2, float* __restrict__ Pout,
    float* __restrict__ SUM, float* __restrict__ SUMQ)
{
    __shared__ __align__(16) short Hl[32][648];
    const int t = threadIdx.x;
    const int wv = t >> 6, lane = t & 63;
    const int m = lane & 15, quad = lane >> 4;
    const int rb = (int)blockIdx.x * 32;

    for (int i = t; i < 32 * 48; i += 256) {
        int r = i / 48, c = 600 + (i - r * 48);
        Hl[r][c] = 0;
    }

    // stage 1
    {
        const short* arow0 = Qb + (size_t)(rb + m) * 320 + quad * 8;
        const short* arow1 = arow0 + (size_t)16 * 320;
        vec4f acc[2][10];
#pragma unroll
        for (int g = 0; g < 2; g++)
#pragma unroll
            for (int cf = 0; cf < 10; cf++) acc[g][cf] = (vec4f)0.f;

#pragma unroll
        for (int kt = 0; kt < 10; kt++) {
            vec8s af0 = *(const vec8s*)(arow0 + kt * 32);
            vec8s af1 = *(const vec8s*)(arow1 + kt * 32);
            const short* wb = W1P + ((size_t)kt * 640 + wv * 160 + m) * 32 + quad * 8;
#pragma unroll
            for (int cf = 0; cf < 10; cf++) {
                vec8s bfr = *(const vec8s*)(wb + cf * 512);
                acc[0][cf] = __builtin_amdgcn_mfma_f32_16x16x32_bf16(af0, bfr, acc[0][cf], 0, 0, 0);
                acc[1][cf] = __builtin_amdgcn_mfma_f32_16x16x32_bf16(af1, bfr, acc[1][cf], 0, 0, 0);
            }
        }
#pragma unroll
        for (int cf = 0; cf < 10; cf++) {
            int col = wv * 160 + cf * 16 + m;
            if (col < D2) {
                float bv = b1[col];
#pragma unroll
                for (int g = 0; g < 2; g++)
#pragma unroll
                    for (int reg = 0; reg < 4; reg++) {
                        float v = acc[g][cf][reg] + bv;
                        Hl[g * 16 + quad * 4 + reg][col] = f2bs(fmaxf(v, 0.f));
                    }
            }
        }
    }
    __syncthreads();

    // stage 2 + fused stats
    {
        vec4f acc[2][6];
#pragma unroll
        for (int g = 0; g < 2; g++)
#pragma unroll
            for (int cf = 0; cf < 6; cf++) acc[g][cf] = (vec4f)0.f;

#pragma unroll
        for (int kt = 0; kt < 19; kt++) {
            vec8s af0 = *(const vec8s*)&Hl[m][kt * 32 + quad * 8];
            vec8s af1 = *(const vec8s*)&Hl[16 + m][kt * 32 + quad * 8];
            const short* wb = W2P + ((size_t)kt * 384 + wv * 96 + m) * 32 + quad * 8;
#pragma unroll
            for (int cf = 0; cf < 6; cf++) {
                vec8s bfr = *(const vec8s*)(wb + cf * 512);
                acc[0][cf] = __builtin_amdgcn_mfma_f32_16x16x32_bf16(af0, bfr, acc[0][cf], 0, 0, 0);
                acc[1][cf] = __builtin_amdgcn_mfma_f32_16x16x32_bf16(af1, bfr, acc[1][cf], 0, 0, 0);
            }
        }
#pragma unroll
        for (int cf = 0; cf < 6; cf++) {
            int gc = wv * 96 + cf * 16 + m;
            bool ok = (gc < DD);
            float bv = ok ? b2[gc] : 0.f;
            float s = 0.f, q = 0.f;
#pragma unroll
            for (int g = 0; g < 2; g++)
#pragma unroll
                for (int reg = 0; reg < 4; reg++) {
                    float v = acc[g][cf][reg] + bv;
                    if (ok) Pout[(size_t)(rb + g * 16 + quad * 4 + reg) * DD + gc] = v;
                    s += v; q += v * v;
                }
            // reduce over quad (lane bits 4,5) — all lanes participate
            s += __shfl_xor(s, 16); s += __shfl_xor(s, 32);
            q += __shfl_xor(q, 16); q += __shfl_xor(q, 32);
            if (ok && quad == 0) {
                atomicAdd(&SUM[gc], s);
                atomicAdd(&SUMQ[gc], q);
            }
        }
    }
}

// ---- direct-fragment MFMA GEMM (embed GEMM only) ----
template<int OUT_BF_RELU, int KT>
__global__ __launch_bounds__(256) void k_dmm(
    const short* __restrict__ A, int lda,
    const short* __restrict__ WP, int npad,
    const float* __restrict__ bias,
    void* __restrict__ out, int ldo, int N, int M, int NCT)
{
    const int t = threadIdx.x;
    const int wv = t >> 6, lane = t & 63;
    const int m = lane & 15, quad = lane >> 4;
    const int rb = (int)blockIdx.x * 64;
    int ga = rb + wv * 16 + m;
    if (ga > M - 1) ga = M - 1;
    const short* arow = A + (size_t)ga * lda + quad * 8;

    for (int ct = 0; ct < NCT; ct++) {
        const int cb = ct * 128;
        vec4f acc[8];
#pragma unroll
        for (int cf = 0; cf < 8; cf++) acc[cf] = (vec4f)0.f;

#pragma unroll
        for (int kt = 0; kt < KT; kt++) {
            vec8s af = *(const vec8s*)(arow + kt * 32);
            const short* wb = WP + ((size_t)kt * npad + cb + m) * 32 + quad * 8;
#pragma unroll
            for (int cf = 0; cf < 8; cf++) {
                vec8s bfr = *(const vec8s*)(wb + cf * 512);
                acc[cf] = __builtin_amdgcn_mfma_f32_16x16x32_bf16(af, bfr, acc[cf], 0, 0, 0);
            }
        }
        int grow0 = rb + wv * 16 + quad * 4;
#pragma unroll
        for (int cf = 0; cf < 8; cf++) {
            int gc = cb + cf * 16 + m;
            if (gc >= N) continue;
            float bv = bias[gc];
#pragma unroll
            for (int reg = 0; reg < 4; reg++) {
                int g = grow0 + reg;
                if (g < M) {
                    float v = acc[cf][reg] + bv;
                    if (OUT_BF_RELU)
                        ((short*)out)[(size_t)g * ldo + gc] = f2bs(fmaxf(v, 0.f));
                    else
                        ((float*)out)[(size_t)g * ldo + gc] = v;
                }
            }
        }
    }
}

// ============ CSR build ============
__global__ void k_degree(const int* __restrict__ dst, int* __restrict__ deg) {
    int e = blockIdx.x * 256 + threadIdx.x;
    if (e < EE) atomicAdd(&deg[dst[e]], 1);
}

__global__ void k_scan1(const int* __restrict__ deg, int* __restrict__ off,
                        int* __restrict__ bsum)
{
    __shared__ int s[256];
    int i = blockIdx.x * 256 + threadIdx.x;
    int v = (i < NN) ? deg[i] : 0;
    s[threadIdx.x] = v;
    __syncthreads();
    for (int o = 1; o < 256; o <<= 1) {
        int tv = (threadIdx.x >= o) ? s[threadIdx.x - o] : 0;
        __syncthreads();
        s[threadIdx.x] += tv;
        __syncthreads();
    }
    if (i < NN) off[i] = s[threadIdx.x] - v;
    if (threadIdx.x == 255) bsum[blockIdx.x] = s[255];
}

__global__ void k_scan2(int* __restrict__ bsum, int* __restrict__ off, int nb) {
    if (threadIdx.x != 0 || blockIdx.x != 0) return;
    int run = 0;
    for (int b = 0; b < nb; b++) { int t = bsum[b]; bsum[b] = run; run += t; }
    off[NN] = run;
}

__global__ void k_scan3(int* __restrict__ off, const int* __restrict__ bsum,
                        int* __restrict__ curs)
{
    int i = blockIdx.x * 256 + threadIdx.x;
    if (i >= NN) return;
    int v = off[i] + bsum[i >> 8];
    off[i] = v;
    curs[i] = v;
}

__global__ void k_fill(const int* __restrict__ dst, int* __restrict__ curs,
                       int* __restrict__ eidx)
{
    int e = blockIdx.x * 256 + threadIdx.x;
    if (e >= EE) return;
    int pos = atomicAdd(&curs[dst[e]], 1);
    eidx[pos] = e;
}

// ============ embed attention -> bf16 rows (stride 320, pads zeroed) ============
__global__ __launch_bounds__(256) void k_embed(
    const int* __restrict__ x, const float* __restrict__ atom_emb,
    const float* __restrict__ att_vec, short* __restrict__ fusedb)
{
    int wave = threadIdx.x >> 6;
    int lane = threadIdx.x & 63;
    int n = blockIdx.x * 4 + wave;
    if (n >= NN) return;

    float att[5];
#pragma unroll
    for (int j = 0; j < 5; j++) {
        int d = lane + 64 * j;
        att[j] = (d < DD) ? att_vec[d] : 0.f;
    }
    float emb[9][5];
    float sc[9];
#pragma unroll
    for (int f = 0; f < 9; f++) {
        int idx = x[n * 9 + f];
        const float* p = atom_emb + (size_t)(f * 119 + idx) * DD;
        float partial = 0.f;
#pragma unroll
        for (int j = 0; j < 5; j++) {
            int d = lane + 64 * j;
            float v = (d < DD) ? p[d] : 0.f;
            emb[f][j] = v;
            partial += v * att[j];
        }
#pragma unroll
        for (int off = 32; off; off >>= 1) partial += __shfl_xor(partial, off, 64);
        sc[f] = partial;
    }
    float mx = sc[0];
#pragma unroll
    for (int f = 1; f < 9; f++) mx = fmaxf(mx, sc[f]);
    float s = 0.f;
#pragma unroll
    for (int f = 0; f < 9; f++) { sc[f] = __expf(sc[f] - mx); s += sc[f]; }
    float inv = 1.f / s;
#pragma unroll
    for (int j = 0; j < 5; j++) {
        int d = lane + 64 * j;
        float acc = 0.f;
        if (d < DD) {
#pragma unroll
            for (int f = 0; f < 9; f++) acc += emb[f][j] * sc[f];
            acc *= inv;
        }
        fusedb[(size_t)n * 320 + d] = (d < DD) ? f2bs(acc) : (short)0;
    }
}

// ---- gaussian basis, CSR gather (plain eidx, before repack) ----
__global__ __launch_bounds__(320) void k_gaussg(
    const int* __restrict__ off, const int* __restrict__ eidx,
    const float* __restrict__ dist, const float* __restrict__ g_means,
    const float* __restrict__ g_stds, const float* __restrict__ scale_p,
    float* __restrict__ H)
{
    int n = blockIdx.x;
    int d = threadIdx.x;
    if (d >= DD) return;
    int beg = off[n], end = off[n + 1];
    if (beg == end) return;
    float sd = fabsf(g_stds[d]) + 0.01f;
    float mean = g_means[d];
    float inv_asd = 1.f / (2.5066263f * sd);
    float sum = 0.f;
    for (int i = beg; i < end; i++) {
        float xv = dist[eidx[i]];
        float z = (xv - mean) / sd;
        sum += __expf(-0.5f * z * z) * inv_asd;
    }
    int deg = end - beg;
    int c = deg - 1; c = c < 0 ? 0 : (c > 3 ? 3 : c);
    H[(size_t)n * DD + d] += __expf(scale_p[c * DD + d]) * sum;
}

// ---- fused aggregation: packed EIDX (src|combo<<17) + combined E table ----
__global__ __launch_bounds__(320) void k_agg(
    const float* __restrict__ P, const int* __restrict__ off,
    const int* __restrict__ eidxp, const float* __restrict__ E,
    const float* __restrict__ scale, const float* __restrict__ shift,
    int apply, short* __restrict__ Qb)
{
    int n = blockIdx.x;
    int d = threadIdx.x;
    if (d >= DD) {
        if (d < 320) Qb[(size_t)n * 320 + d] = 0;
        return;
    }
    float sc = apply ? scale[d] : 1.f;
    float sh = apply ? shift[d] : 0.f;
    float self = P[(size_t)n * DD + d];
    if (apply) self = fmaxf(self * sc + sh, 0.f);
    float acc = self + E[24 * DD + d];          // self-loop combo
    int beg = off[n], end = off[n + 1];
    for (int i = beg; i < end; i++) {
        int v = eidxp[i];
        int s = v & 131071;
        int c = v >> 17;
        float pv = P[(size_t)s * DD + d];
        if (apply) pv = fmaxf(pv * sc + sh, 0.f);
        acc += pv + E[c * DD + d];
    }
    Qb[(size_t)n * 320 + d] = f2bs(acc);
}

__global__ void k_bnprep(float* __restrict__ sum, float* __restrict__ sumsq,
                         const float* __restrict__ gamma,
                         const float* __restrict__ beta)
{
    int d = threadIdx.x + blockIdx.x * 256;
    if (d >= DD) return;
    float mu = sum[d] * (1.f / NN);
    float var = sumsq[d] * (1.f / NN) - mu * mu;
    var = fmaxf(var, 0.f);
    float sc = gamma[d] * rsqrtf(var + 1e-5f);
    sum[d] = sc;
    sumsq[d] = beta[d] - mu * sc;
}

// ============ pooling + head ============
__global__ void k_count(const int* __restrict__ batch, float* __restrict__ cnt) {
    int n = blockIdx.x * 256 + threadIdx.x;
    if (n < NN) atomicAdd(&cnt[batch[n]], 1.0f);
}

__global__ __launch_bounds__(320) void k_pool(const float* __restrict__ H,
                                              const int* __restrict__ batch,
                                              float* __restrict__ HG)
{
    __shared__ int sb[ROWS_PER];
    int r0 = blockIdx.x * ROWS_PER;
    int rend = min(r0 + ROWS_PER, NN);
    for (int i = threadIdx.x; i < rend - r0; i += 320) sb[i] = batch[r0 + i];
    __syncthreads();
    int d = threadIdx.x;
    if (d >= DD) return;
    int cur = sb[0];
    float acc = 0.f;
    for (int r = r0; r < rend; r++) {
        int b = sb[r - r0];
        if (b != cur) { atomicAdd(&HG[(size_t)cur * DD + d], acc); acc = 0.f; cur = b; }
        acc += H[(size_t)r * DD + d];
    }
    atomicAdd(&HG[(size_t)cur * DD + d], acc);
}

__global__ void k_hgdiv(float* __restrict__ HG, const float* __restrict__ cnt,
                        const float* __restrict__ scale,
                        const float* __restrict__ shift)
{
    int idx = blockIdx.x * 256 + threadIdx.x;
    if (idx >= GG * DD) return;
    int d = idx % DD;
    float mean = HG[idx] / fmaxf(cnt[idx / DD], 1.0f);
    HG[idx] = mean * scale[d] + shift[d];
}

__global__ __launch_bounds__(256) void k_gemm(
    const float* __restrict__ A, const float* __restrict__ W,
    const float* __restrict__ bias, float* __restrict__ Cf,
    float* __restrict__ Cout, int M, int K, int Ncol, int relu)
{
    extern __shared__ float Ash[];
    int tx = threadIdx.x & 15;
    int ty = threadIdx.x >> 4;
    int rb = blockIdx.y * 16;
    int col = blockIdx.x * 16 + tx;

    for (int idx = threadIdx.x; idx < 16 * K; idx += 256) {
        int r = idx / K, k = idx - r * K;
        int row = rb + r;
        Ash[idx] = (row < M) ? A[(size_t)row * K + k] : 0.f;
    }
    __syncthreads();

    if (col < Ncol) {
        float acc = bias[col];
        const float* a = Ash + ty * K;
        const float* w = W + col;
        for (int k = 0; k < K; k++) acc += a[k] * w[(size_t)k * Ncol];
        if (relu) acc = fmaxf(acc, 0.f);
        int row = rb + ty;
        if (row < M) {
            if (Cf)   Cf[(size_t)row * Ncol + col] = acc;
            if (Cout) Cout[(size_t)row * Ncol + col] = acc;
        }
    }
}

extern "C" void kernel_launch(void* const* d_in, const int* in_sizes, int n_in,
                              void* d_out, int out_size, void* d_ws, size_t ws_size,
                              hipStream_t stream)
{
    const int*   x          = (const int*)  d_in[0];
    const int*   edge_index = (const int*)  d_in[1];
    const int*   edge_attr  = (const int*)  d_in[2];
    const float* edge_dist  = (const float*)d_in[3];
    const int*   batch      = (const int*)  d_in[4];
    const float* atom_emb   = (const float*)d_in[5];
    const float* att_vec    = (const float*)d_in[6];
    const float* out_lin_w  = (const float*)d_in[7];
    const float* out_lin_b  = (const float*)d_in[8];
    const float* g_means    = (const float*)d_in[9];
    const float* g_stds     = (const float*)d_in[10];
    const float* scale_p    = (const float*)d_in[11];
    const float* edge_emb   = (const float*)d_in[12];
    const float* mlp_w1     = (const float*)d_in[13];
    const float* mlp_b1     = (const float*)d_in[14];
    const float* mlp_w2     = (const float*)d_in[15];
    const float* mlp_b2     = (const float*)d_in[16];
    const float* bn_gamma   = (const float*)d_in[17];
    const float* bn_beta    = (const float*)d_in[18];
    const float* feat_w     = (const float*)d_in[19];
    const float* feat_b     = (const float*)d_in[20];
    const float* ol_w1      = (const float*)d_in[21];
    const float* ol_b1      = (const float*)d_in[22];
    const float* ol_w2      = (const float*)d_in[23];
    const float* ol_b2      = (const float*)d_in[24];
    (void)in_sizes; (void)n_in; (void)out_size; (void)ws_size;

    const int* srcp = edge_index;
    const int* dstp = edge_index + EE;

    char* ws = (char*)d_ws;
    size_t off_b = 0;
    auto alloc = [&](size_t bytes) -> char* {
        char* p = ws + off_b;
        off_b += (bytes + 255) & ~(size_t)255;
        return p;
    };
    float* H     = (float*)alloc((size_t)NN * DD * 4 + 256);
    float* AGG   = (float*)alloc((size_t)NN * DD * 4 + 256);
    int*   DEG   = (int*)  alloc((size_t)NN * 4);
    float* SUM   = (float*)alloc(2 * DD * 4);              // SUM | SUMQ contiguous
    float* SUMQ  = SUM + DD;
    float* CNT   = (float*)alloc(GG * 4);
    float* HG    = (float*)alloc((size_t)GG * DD * 4);     // } pool 10,592,000 B
    float* HFEAT = (float*)alloc((size_t)GG * FEATN * 4);  // } packed W + CSR + E
    float* TMP   = (float*)alloc((size_t)GG * FEATN * 4);  // } during loop

    short* OLWP = (short*)HG;                        //   245,760 B
    short* W1P  = OLWP + (size_t)10 * 384 * 32;      // 2,048,000 B
    short* W2P  = W1P + (size_t)LL * 10 * 640 * 32;  // 2,334,720 B
    char*  csr  = (char*)(W2P + (size_t)LL * 19 * 384 * 32);
    int*   OFF  = (int*)csr;                         //   400,128 B
    int*   CURS = (int*)(csr + 400128);              //   400,128 B
    int*   EIDX = (int*)(csr + 800128);              //   800,128 B
    float* ETAB = (float*)(csr + 1600256);           // 5*25*300*4 = 150,000 B
    int*   BSUM = (int*)CNT;                         // total 6,408,736 <= pool

    float* outp = (float*)d_out;

    // prepack weights + combined edge tables
    k_pack<<<480, 256, 0, stream>>>(out_lin_w, OLWP, 300, 300, 10, 384);
    for (int l = 0; l < LL; l++) {
        k_pack<<<800, 256, 0, stream>>>(mlp_w1 + (size_t)l * DD * D2,
                                        W1P + (size_t)l * 10 * 640 * 32, DD, D2, 10, 640);
        k_pack<<<912, 256, 0, stream>>>(mlp_w2 + (size_t)l * D2 * DD,
                                        W2P + (size_t)l * 19 * 384 * 32, D2, DD, 19, 384);
    }
    k_etab<<<(LL * 25 * DD + 255) / 256, 256, 0, stream>>>(edge_emb, ETAB);

    // CSR build
    hipMemsetAsync(DEG, 0, (size_t)NN * 4, stream);
    k_degree<<<(EE + 255) / 256, 256, 0, stream>>>(dstp, DEG);
    k_scan1<<<391, 256, 0, stream>>>(DEG, OFF, BSUM);
    k_scan2<<<1, 64, 0, stream>>>(BSUM, OFF, 391);
    k_scan3<<<391, 256, 0, stream>>>(OFF, BSUM, CURS);
    k_fill<<<(EE + 255) / 256, 256, 0, stream>>>(dstp, CURS, EIDX);

    // node init
    short* QB = (short*)AGG;
    k_embed<<<(NN + 3) / 4, 256, 0, stream>>>(x, atom_emb, att_vec, QB);
    k_dmm<0, 10><<<(NN + 63) / 64, 256, 0, stream>>>(
        QB, 320, OLWP, 384, out_lin_b, H, DD, DD, NN, 3);
    k_gaussg<<<NN, 320, 0, stream>>>(OFF, EIDX, edge_dist, g_means, g_stds,
                                     scale_p, H);
    // pack EIDX -> src | combo<<17 (gauss consumed the plain form)
    k_repack<<<(EE + 255) / 256, 256, 0, stream>>>(EIDX, srcp, edge_attr);

    // layer loop
    for (int l = 0; l < LL; l++) {
        k_agg<<<NN, 320, 0, stream>>>(H, OFF, EIDX, ETAB + (size_t)l * 25 * DD,
                                      SUM, SUMQ, l > 0 ? 1 : 0, QB);
        hipMemsetAsync(SUM, 0, 2 * DD * 4, stream);
        k_mlp2<<<NN / 32, 256, 0, stream>>>(
            QB, W1P + (size_t)l * 10 * 640 * 32, mlp_b1 + (size_t)l * D2,
            W2P + (size_t)l * 19 * 384 * 32, mlp_b2 + (size_t)l * DD, H,
            SUM, SUMQ);
        k_bnprep<<<2, 256, 0, stream>>>(SUM, SUMQ, bn_gamma + (size_t)l * DD,
                                        bn_beta + (size_t)l * DD);
    }

    // pooling; last BN folded into k_hgdiv
    hipMemsetAsync(CNT, 0, (size_t)GG * 4, stream);
    hipMemsetAsync(HG, 0, (size_t)GG * DD * 4, stream);
    k_count<<<(NN + 255) / 256, 256, 0, stream>>>(batch, CNT);
    k_pool<<<(NN + ROWS_PER - 1) / ROWS_PER, 320, 0, stream>>>(H, batch, HG);
    k_hgdiv<<<(GG * DD + 255) / 256, 256, 0, stream>>>(HG, CNT, SUM, SUMQ);
    {
        dim3 grid((FEATN + 15) / 16, (GG + 15) / 16);
        k_gemm<<<grid, 256, 16 * DD * 4, stream>>>(HG, feat_w, feat_b, HFEAT, outp,
                                                   GG, DD, FEATN, 0);
    }
    {
        dim3 grid((FEATN + 15) / 16, (GG + 15) / 16);
        k_gemm<<<grid, 256, 16 * FEATN * 4, stream>>>(HFEAT, ol_w1, ol_b1, TMP, nullptr,
                                                      GG, FEATN, FEATN, 1);
    }
    {
        dim3 grid((OUT2 + 15) / 16, (GG + 15) / 16);
        k_gemm<<<grid, 256, 16 * FEATN * 4, stream>>>(TMP, ol_w2, ol_b2, nullptr,
                                                      outp + (size_t)GG * FEATN,
                                                      GG, FEATN, OUT2, 0);
    }
}

// Round 14
// 2795.812 us; speedup vs baseline: 1.7023x; 1.1480x over previous
//
#include <hip/hip_runtime.h>
#include <hip/hip_bf16.h>

// GINet forward, fp32 in/out. R14: (1) fused BN-stats de-contended via 32
// replicas/layer (atomic contention 3125->98 per address); (2) embed GEMM in
// k_mlp2-stage1 shape (k_g1); (3) k_agg float2 gather, 2 nodes/block; (4)
// per-layer scale/shift buffers — per-layer memsets gone.

#define NN   100000
#define EE   200000
#define GG   2000
#define DD   300
#define D2   600
#define LL   5
#define FEATN 512
#define OUT2 256
#define ROWS_PER 256

typedef __hip_bfloat16 bf16;
typedef short vec8s __attribute__((ext_vector_type(8)));
typedef float vec4f __attribute__((ext_vector_type(4)));

__device__ __forceinline__ short f2bs(float v) {
    bf16 h = __float2bfloat16(v);
    return __builtin_bit_cast(short, h);
}

// ---- weight prepack: src[K][N] fp32 -> dst[kt][col<NPAD][32] bf16 ----
__global__ void k_pack(const float* __restrict__ src, short* __restrict__ dst,
                       int Ksrc, int Nsrc, int KT, int NPAD)
{
    int idx = blockIdx.x * 256 + threadIdx.x;
    int total = KT * NPAD * 32;
    if (idx >= total) return;
    int col = idx % NPAD;
    int tmp = idx / NPAD;
    int kk  = tmp % 32;
    int kt  = tmp / 32;
    int k = kt * 32 + kk;
    short v = 0;
    if (k < Ksrc && col < Nsrc) v = f2bs(src[(size_t)k * Nsrc + col]);
    dst[((size_t)kt * NPAD + col) * 32 + kk] = v;
}

// ---- combined edge-emb tables: E[l][c][d], c<24 = a0*6+a1*2+a2, c==24 self ----
__global__ void k_etab(const float* __restrict__ edge_emb, float* __restrict__ E)
{
    int i = blockIdx.x * 256 + threadIdx.x;
    if (i >= LL * 25 * DD) return;
    int d = i % DD;
    int t = i / DD;
    int c = t % 25;
    int l = t / 25;
    int a0 = (c == 24) ? 4 : (c / 6);
    int a1 = (c == 24) ? 0 : ((c % 6) / 2);
    int a2 = (c == 24) ? 0 : (c % 2);
    const float* e0 = edge_emb + (size_t)((l * 3 + 0) * 5) * DD;
    const float* e1 = edge_emb + (size_t)((l * 3 + 1) * 5) * DD;
    const float* e2 = edge_emb + (size_t)((l * 3 + 2) * 5) * DD;
    E[i] = e0[a0 * DD + d] + e1[a1 * DD + d] + e2[a2 * DD + d];
}

// ---- repack EIDX: edge id -> src | (combo<<17) ----
__global__ void k_repack(int* __restrict__ eidx, const int* __restrict__ src,
                         const int* __restrict__ attr)
{
    int i = blockIdx.x * 256 + threadIdx.x;
    if (i >= EE) return;
    int e = eidx[i];
    int c = attr[e * 3] * 6 + attr[e * 3 + 1] * 2 + attr[e * 3 + 2];
    eidx[i] = src[e] | (c << 17);
}

// ---- fused MLP layer + replicated BN stats ----
__global__ __launch_bounds__(256) void k_mlp2(
    const short* __restrict__ Qb, const short* __restrict__ W1P,
    const float* __restrict__ b1, const short* __restrict__ W2P,
    const float* __restrict__ b2, float* __restrict__ Pout,
    float* __restrict__ RS)            // [2][32][600] partial sums for layer
{
    __shared__ __align__(16) short Hl[32][648];
    const int t = threadIdx.x;
    const int wv = t >> 6, lane = t & 63;
    const int m = lane & 15, quad = lane >> 4;
    const int rb = (int)blockIdx.x * 32;
    const int rep = ((int)blockIdx.x & 31) * 600;

    for (int i = t; i < 32 * 48; i += 256) {
        int r = i / 48, c = 600 + (i - r * 48);
        Hl[r][c] = 0;
    }

    // stage 1
    {
        const short* arow0 = Qb + (size_t)(rb + m) * 320 + quad * 8;
        const short* arow1 = arow0 + (size_t)16 * 320;
        vec4f acc[2][10];
#pragma unroll
        for (int g = 0; g < 2; g++)
#pragma unroll
            for (int cf = 0; cf < 10; cf++) acc[g][cf] = (vec4f)0.f;

#pragma unroll
        for (int kt = 0; kt < 10; kt++) {
            vec8s af0 = *(const vec8s*)(arow0 + kt * 32);
            vec8s af1 = *(const vec8s*)(arow1 + kt * 32);
            const short* wb = W1P + ((size_t)kt * 640 + wv * 160 + m) * 32 + quad * 8;
#pragma unroll
            for (int cf = 0; cf < 10; cf++) {
                vec8s bfr = *(const vec8s*)(wb + cf * 512);
                acc[0][cf] = __builtin_amdgcn_mfma_f32_16x16x32_bf16(af0, bfr, acc[0][cf], 0, 0, 0);
                acc[1][cf] = __builtin_amdgcn_mfma_f32_16x16x32_bf16(af1, bfr, acc[1][cf], 0, 0, 0);
            }
        }
#pragma unroll
        for (int cf = 0; cf < 10; cf++) {
            int col = wv * 160 + cf * 16 + m;
            if (col < D2) {
                float bv = b1[col];
#pragma unroll
                for (int g = 0; g < 2; g++)
#pragma unroll
                    for (int reg = 0; reg < 4; reg++) {
                        float v = acc[g][cf][reg] + bv;
                        Hl[g * 16 + quad * 4 + reg][col] = f2bs(fmaxf(v, 0.f));
                    }
            }
        }
    }
    __syncthreads();

    // stage 2 + stats into replica
    {
        vec4f acc[2][6];
#pragma unroll
        for (int g = 0; g < 2; g++)
#pragma unroll
            for (int cf = 0; cf < 6; cf++) acc[g][cf] = (vec4f)0.f;

#pragma unroll
        for (int kt = 0; kt < 19; kt++) {
            vec8s af0 = *(const vec8s*)&Hl[m][kt * 32 + quad * 8];
            vec8s af1 = *(const vec8s*)&Hl[16 + m][kt * 32 + quad * 8];
            const short* wb = W2P + ((size_t)kt * 384 + wv * 96 + m) * 32 + quad * 8;
#pragma unroll
            for (int cf = 0; cf < 6; cf++) {
                vec8s bfr = *(const vec8s*)(wb + cf * 512);
                acc[0][cf] = __builtin_amdgcn_mfma_f32_16x16x32_bf16(af0, bfr, acc[0][cf], 0, 0, 0);
                acc[1][cf] = __builtin_amdgcn_mfma_f32_16x16x32_bf16(af1, bfr, acc[1][cf], 0, 0, 0);
            }
        }
#pragma unroll
        for (int cf = 0; cf < 6; cf++) {
            int gc = wv * 96 + cf * 16 + m;
            bool ok = (gc < DD);
            float bv = ok ? b2[gc] : 0.f;
            float s = 0.f, q = 0.f;
#pragma unroll
            for (int g = 0; g < 2; g++)
#pragma unroll
                for (int reg = 0; reg < 4; reg++) {
                    float v = acc[g][cf][reg] + bv;
                    if (ok) Pout[(size_t)(rb + g * 16 + quad * 4 + reg) * DD + gc] = v;
                    s += v; q += v * v;
                }
            s += __shfl_xor(s, 16); s += __shfl_xor(s, 32);
            q += __shfl_xor(q, 16); q += __shfl_xor(q, 32);
            if (ok && quad == 0) {
                atomicAdd(&RS[rep + gc], s);
                atomicAdd(&RS[19200 + rep + gc], q);
            }
        }
    }
}

// ---- embed GEMM, k_mlp2-stage1 shape: H = Qb @ OLWP + bias (fp32 out) ----
__global__ __launch_bounds__(256) void k_g1(
    const short* __restrict__ Qb, const short* __restrict__ WP,
    const float* __restrict__ bias, float* __restrict__ H)
{
    const int t = threadIdx.x;
    const int wv = t >> 6, lane = t & 63;
    const int m = lane & 15, quad = lane >> 4;
    const int rb = (int)blockIdx.x * 32;
    const short* arow0 = Qb + (size_t)(rb + m) * 320 + quad * 8;
    const short* arow1 = arow0 + (size_t)16 * 320;

    vec4f acc[2][5];
#pragma unroll
    for (int g = 0; g < 2; g++)
#pragma unroll
        for (int cf = 0; cf < 5; cf++) acc[g][cf] = (vec4f)0.f;

#pragma unroll
    for (int kt = 0; kt < 10; kt++) {
        vec8s af0 = *(const vec8s*)(arow0 + kt * 32);
        vec8s af1 = *(const vec8s*)(arow1 + kt * 32);
        const short* wb = WP + ((size_t)kt * 384 + wv * 80 + m) * 32 + quad * 8;
#pragma unroll
        for (int cf = 0; cf < 5; cf++) {
            vec8s bfr = *(const vec8s*)(wb + cf * 512);
            acc[0][cf] = __builtin_amdgcn_mfma_f32_16x16x32_bf16(af0, bfr, acc[0][cf], 0, 0, 0);
            acc[1][cf] = __builtin_amdgcn_mfma_f32_16x16x32_bf16(af1, bfr, acc[1][cf], 0, 0, 0);
        }
    }
#pragma unroll
    for (int cf = 0; cf < 5; cf++) {
        int gc = wv * 80 + cf * 16 + m;
        if (gc >= DD) continue;
        float bv = bias[gc];
#pragma unroll
        for (int g = 0; g < 2; g++)
#pragma unroll
            for (int reg = 0; reg < 4; reg++)
                H[(size_t)(rb + g * 16 + quad * 4 + reg) * DD + gc] = acc[g][cf][reg] + bv;
    }
}

// ============ CSR build ============
__global__ void k_degree(const int* __restrict__ dst, int* __restrict__ deg) {
    int e = blockIdx.x * 256 + threadIdx.x;
    if (e < EE) atomicAdd(&deg[dst[e]], 1);
}

__global__ void k_scan1(const int* __restrict__ deg, int* __restrict__ off,
                        int* __restrict__ bsum)
{
    __shared__ int s[256];
    int i = blockIdx.x * 256 + threadIdx.x;
    int v = (i < NN) ? deg[i] : 0;
    s[threadIdx.x] = v;
    __syncthreads();
    for (int o = 1; o < 256; o <<= 1) {
        int tv = (threadIdx.x >= o) ? s[threadIdx.x - o] : 0;
        __syncthreads();
        s[threadIdx.x] += tv;
        __syncthreads();
    }
    if (i < NN) off[i] = s[threadIdx.x] - v;
    if (threadIdx.x == 255) bsum[blockIdx.x] = s[255];
}

__global__ void k_scan2(int* __restrict__ bsum, int* __restrict__ off, int nb) {
    if (threadIdx.x != 0 || blockIdx.x != 0) return;
    int run = 0;
    for (int b = 0; b < nb; b++) { int t = bsum[b]; bsum[b] = run; run += t; }
    off[NN] = run;
}

__global__ void k_scan3(int* __restrict__ off, const int* __restrict__ bsum,
                        int* __restrict__ curs)
{
    int i = blockIdx.x * 256 + threadIdx.x;
    if (i >= NN) return;
    int v = off[i] + bsum[i >> 8];
    off[i] = v;
    curs[i] = v;
}

__global__ void k_fill(const int* __restrict__ dst, int* __restrict__ curs,
                       int* __restrict__ eidx)
{
    int e = blockIdx.x * 256 + threadIdx.x;
    if (e >= EE) return;
    int pos = atomicAdd(&curs[dst[e]], 1);
    eidx[pos] = e;
}

// ============ embed attention -> bf16 rows (stride 320, pads zeroed) ============
__global__ __launch_bounds__(256) void k_embed(
    const int* __restrict__ x, const float* __restrict__ atom_emb,
    const float* __restrict__ att_vec, short* __restrict__ fusedb)
{
    int wave = threadIdx.x >> 6;
    int lane = threadIdx.x & 63;
    int n = blockIdx.x * 4 + wave;
    if (n >= NN) return;

    float att[5];
#pragma unroll
    for (int j = 0; j < 5; j++) {
        int d = lane + 64 * j;
        att[j] = (d < DD) ? att_vec[d] : 0.f;
    }
    float emb[9][5];
    float sc[9];
#pragma unroll
    for (int f = 0; f < 9; f++) {
        int idx = x[n * 9 + f];
        const float* p = atom_emb + (size_t)(f * 119 + idx) * DD;
        float partial = 0.f;
#pragma unroll
        for (int j = 0; j < 5; j++) {
            int d = lane + 64 * j;
            float v = (d < DD) ? p[d] : 0.f;
            emb[f][j] = v;
            partial += v * att[j];
        }
#pragma unroll
        for (int off = 32; off; off >>= 1) partial += __shfl_xor(partial, off, 64);
        sc[f] = partial;
    }
    float mx = sc[0];
#pragma unroll
    for (int f = 1; f < 9; f++) mx = fmaxf(mx, sc[f]);
    float s = 0.f;
#pragma unroll
    for (int f = 0; f < 9; f++) { sc[f] = __expf(sc[f] - mx); s += sc[f]; }
    float inv = 1.f / s;
#pragma unroll
    for (int j = 0; j < 5; j++) {
        int d = lane + 64 * j;
        float acc = 0.f;
        if (d < DD) {
#pragma unroll
            for (int f = 0; f < 9; f++) acc += emb[f][j] * sc[f];
            acc *= inv;
        }
        fusedb[(size_t)n * 320 + d] = (d < DD) ? f2bs(acc) : (short)0;
    }
}

// ---- gaussian basis, CSR gather ----
__global__ __launch_bounds__(320) void k_gaussg(
    const int* __restrict__ off, const int* __restrict__ eidx,
    const float* __restrict__ dist, const float* __restrict__ g_means,
    const float* __restrict__ g_stds, const float* __restrict__ scale_p,
    float* __restrict__ H)
{
    int n = blockIdx.x;
    int d = threadIdx.x;
    if (d >= DD) return;
    int beg = off[n], end = off[n + 1];
    if (beg == end) return;
    float sd = fabsf(g_stds[d]) + 0.01f;
    float mean = g_means[d];
    float inv_asd = 1.f / (2.5066263f * sd);
    float sum = 0.f;
    for (int i = beg; i < end; i++) {
        float xv = dist[eidx[i]];
        float z = (xv - mean) / sd;
        sum += __expf(-0.5f * z * z) * inv_asd;
    }
    int deg = end - beg;
    int c = deg - 1; c = c < 0 ? 0 : (c > 3 ? 3 : c);
    H[(size_t)n * DD + d] += __expf(scale_p[c * DD + d]) * sum;
}

// ---- fused aggregation, float2, 2 nodes/block ----
__global__ __launch_bounds__(320) void k_agg(
    const float* __restrict__ P, const int* __restrict__ off,
    const int* __restrict__ eidxp, const float* __restrict__ E,
    const float* __restrict__ scale, const float* __restrict__ shift,
    int apply, short* __restrict__ Qb)
{
    int tn = threadIdx.x / 160;
    int td = threadIdx.x - tn * 160;
    int n = blockIdx.x * 2 + tn;
    if (n >= NN) return;
    int d2 = td * 2;
    if (d2 >= DD) {   // 300..318 -> zero pads (covers 300..319)
        *(short*)&Qb[(size_t)n * 320 + d2] = 0;
        Qb[(size_t)n * 320 + d2 + 1] = 0;
        return;
    }
    float scx = 1.f, scy = 1.f, shx = 0.f, shy = 0.f;
    if (apply) {
        float2 s2 = *(const float2*)(scale + d2);
        float2 h2 = *(const float2*)(shift + d2);
        scx = s2.x; scy = s2.y; shx = h2.x; shy = h2.y;
    }
    float2 self = *(const float2*)(P + (size_t)n * DD + d2);
    float ax, ay;
    if (apply) {
        ax = fmaxf(self.x * scx + shx, 0.f);
        ay = fmaxf(self.y * scy + shy, 0.f);
    } else { ax = self.x; ay = self.y; }
    float2 es = *(const float2*)(E + 24 * DD + d2);
    ax += es.x; ay += es.y;
    int beg = off[n], end = off[n + 1];
    for (int i = beg; i < end; i++) {
        int v = eidxp[i];
        int s = v & 131071;
        int c = v >> 17;
        float2 pv = *(const float2*)(P + (size_t)s * DD + d2);
        float px, py;
        if (apply) {
            px = fmaxf(pv.x * scx + shx, 0.f);
            py = fmaxf(pv.y * scy + shy, 0.f);
        } else { px = pv.x; py = pv.y; }
        float2 ev = *(const float2*)(E + c * DD + d2);
        ax += px + ev.x; ay += py + ev.y;
    }
    short2 o; o.x = f2bs(ax); o.y = f2bs(ay);
    *(short2*)&Qb[(size_t)n * 320 + d2] = o;
}

// ---- reduce 32 replicas -> scale/shift for the layer ----
__global__ void k_bnprep(const float* __restrict__ RS, float* __restrict__ SC,
                         const float* __restrict__ gamma,
                         const float* __restrict__ beta)
{
    int d = threadIdx.x + blockIdx.x * 256;
    if (d >= DD) return;
    float s = 0.f, q = 0.f;
    for (int r = 0; r < 32; r++) {
        s += RS[r * 600 + d];
        q += RS[19200 + r * 600 + d];
    }
    float mu = s * (1.f / NN);
    float var = q * (1.f / NN) - mu * mu;
    var = fmaxf(var, 0.f);
    float sc = gamma[d] * rsqrtf(var + 1e-5f);
    SC[d] = sc;
    SC[600 + d] = beta[d] - mu * sc;
}

// ============ pooling + head ============
__global__ void k_count(const int* __restrict__ batch, float* __restrict__ cnt) {
    int n = blockIdx.x * 256 + threadIdx.x;
    if (n < NN) atomicAdd(&cnt[batch[n]], 1.0f);
}

__global__ __launch_bounds__(320) void k_pool(const float* __restrict__ H,
                                              const int* __restrict__ batch,
                                              float* __restrict__ HG)
{
    __shared__ int sb[ROWS_PER];
    int r0 = blockIdx.x * ROWS_PER;
    int rend = min(r0 + ROWS_PER, NN);
    for (int i = threadIdx.x; i < rend - r0; i += 320) sb[i] = batch[r0 + i];
    __syncthreads();
    int d = threadIdx.x;
    if (d >= DD) return;
    int cur = sb[0];
    float acc = 0.f;
    for (int r = r0; r < rend; r++) {
        int b = sb[r - r0];
        if (b != cur) { atomicAdd(&HG[(size_t)cur * DD + d], acc); acc = 0.f; cur = b; }
        acc += H[(size_t)r * DD + d];
    }
    atomicAdd(&HG[(size_t)cur * DD + d], acc);
}

__global__ void k_hgdiv(float* __restrict__ HG, const float* __restrict__ cnt,
                        const float* __restrict__ SC)
{
    int idx = blockIdx.x * 256 + threadIdx.x;
    if (idx >= GG * DD) return;
    int d = idx % DD;
    float mean = HG[idx] / fmaxf(cnt[idx / DD], 1.0f);
    HG[idx] = mean * SC[d] + SC[600 + d];
}

__global__ __launch_bounds__(256) void k_gemm(
    const float* __restrict__ A, const float* __restrict__ W,
    const float* __restrict__ bias, float* __restrict__ Cf,
    float* __restrict__ Cout, int M, int K, int Ncol, int relu)
{
    extern __shared__ float Ash[];
    int tx = threadIdx.x & 15;
    int ty = threadIdx.x >> 4;
    int rb = blockIdx.y * 16;
    int col = blockIdx.x * 16 + tx;

    for (int idx = threadIdx.x; idx < 16 * K; idx += 256) {
        int r = idx / K, k = idx - r * K;
        int row = rb + r;
        Ash[idx] = (row < M) ? A[(size_t)row * K + k] : 0.f;
    }
    __syncthreads();

    if (col < Ncol) {
        float acc = bias[col];
        const float* a = Ash + ty * K;
        const float* w = W + col;
        for (int k = 0; k < K; k++) acc += a[k] * w[(size_t)k * Ncol];
        if (relu) acc = fmaxf(acc, 0.f);
        int row = rb + ty;
        if (row < M) {
            if (Cf)   Cf[(size_t)row * Ncol + col] = acc;
            if (Cout) Cout[(size_t)row * Ncol + col] = acc;
        }
    }
}

extern "C" void kernel_launch(void* const* d_in, const int* in_sizes, int n_in,
                              void* d_out, int out_size, void* d_ws, size_t ws_size,
                              hipStream_t stream)
{
    const int*   x          = (const int*)  d_in[0];
    const int*   edge_index = (const int*)  d_in[1];
    const int*   edge_attr  = (const int*)  d_in[2];
    const float* edge_dist  = (const float*)d_in[3];
    const int*   batch      = (const int*)  d_in[4];
    const float* atom_emb   = (const float*)d_in[5];
    const float* att_vec    = (const float*)d_in[6];
    const float* out_lin_w  = (const float*)d_in[7];
    const float* out_lin_b  = (const float*)d_in[8];
    const float* g_means    = (const float*)d_in[9];
    const float* g_stds     = (const float*)d_in[10];
    const float* scale_p    = (const float*)d_in[11];
    const float* edge_emb   = (const float*)d_in[12];
    const float* mlp_w1     = (const float*)d_in[13];
    const float* mlp_b1     = (const float*)d_in[14];
    const float* mlp_w2     = (const float*)d_in[15];
    const float* mlp_b2     = (const float*)d_in[16];
    const float* bn_gamma   = (const float*)d_in[17];
    const float* bn_beta    = (const float*)d_in[18];
    const float* feat_w     = (const float*)d_in[19];
    const float* feat_b     = (const float*)d_in[20];
    const float* ol_w1      = (const float*)d_in[21];
    const float* ol_b1      = (const float*)d_in[22];
    const float* ol_w2      = (const float*)d_in[23];
    const float* ol_b2      = (const float*)d_in[24];
    (void)in_sizes; (void)n_in; (void)out_size; (void)ws_size;

    const int* srcp = edge_index;
    const int* dstp = edge_index + EE;

    char* ws = (char*)d_ws;
    size_t off_b = 0;
    auto alloc = [&](size_t bytes) -> char* {
        char* p = ws + off_b;
        off_b += (bytes + 255) & ~(size_t)255;
        return p;
    };
    float* H     = (float*)alloc((size_t)NN * DD * 4 + 256);
    float* AGG   = (float*)alloc((size_t)NN * DD * 4 + 256);
    int*   DEG   = (int*)  alloc((size_t)NN * 4);
    float* CNT   = (float*)alloc(GG * 4);
    float* HG    = (float*)alloc((size_t)GG * DD * 4);     // } pool 10,592,000 B
    float* HFEAT = (float*)alloc((size_t)GG * FEATN * 4);  // } packed W + CSR +
    float* TMP   = (float*)alloc((size_t)GG * FEATN * 4);  // } ETAB + REPS + SCL

    short* OLWP = (short*)HG;                        //   245,760 B
    short* W1P  = OLWP + (size_t)10 * 384 * 32;      // 2,048,000 B
    short* W2P  = W1P + (size_t)LL * 10 * 640 * 32;  // 2,334,720 B
    char*  csr  = (char*)(W2P + (size_t)LL * 19 * 384 * 32);
    int*   OFF  = (int*)csr;                         //   400,128
    int*   CURS = (int*)(csr + 400128);              //   400,128
    int*   EIDX = (int*)(csr + 800128);              //   800,128
    float* ETAB = (float*)(csr + 1600256);           //   150,000
    float* REPS = (float*)(csr + 1750272);           // 5*2*32*600*4 = 768,000
    float* SCL  = (float*)(csr + 2518528);           // 5*1200*4 = 24,000
    int*   BSUM = (int*)CNT;                         // end csr+2,542,528 <= pool

    float* outp = (float*)d_out;

    // prepack weights + combined edge tables
    k_pack<<<480, 256, 0, stream>>>(out_lin_w, OLWP, 300, 300, 10, 384);
    for (int l = 0; l < LL; l++) {
        k_pack<<<800, 256, 0, stream>>>(mlp_w1 + (size_t)l * DD * D2,
                                        W1P + (size_t)l * 10 * 640 * 32, DD, D2, 10, 640);
        k_pack<<<912, 256, 0, stream>>>(mlp_w2 + (size_t)l * D2 * DD,
                                        W2P + (size_t)l * 19 * 384 * 32, D2, DD, 19, 384);
    }
    k_etab<<<(LL * 25 * DD + 255) / 256, 256, 0, stream>>>(edge_emb, ETAB);
    hipMemsetAsync(REPS, 0, (size_t)LL * 2 * 32 * 600 * 4, stream);

    // CSR build
    hipMemsetAsync(DEG, 0, (size_t)NN * 4, stream);
    k_degree<<<(EE + 255) / 256, 256, 0, stream>>>(dstp, DEG);
    k_scan1<<<391, 256, 0, stream>>>(DEG, OFF, BSUM);
    k_scan2<<<1, 64, 0, stream>>>(BSUM, OFF, 391);
    k_scan3<<<391, 256, 0, stream>>>(OFF, BSUM, CURS);
    k_fill<<<(EE + 255) / 256, 256, 0, stream>>>(dstp, CURS, EIDX);

    // node init
    short* QB = (short*)AGG;
    k_embed<<<(NN + 3) / 4, 256, 0, stream>>>(x, atom_emb, att_vec, QB);
    k_g1<<<NN / 32, 256, 0, stream>>>(QB, OLWP, out_lin_b, H);
    k_gaussg<<<NN, 320, 0, stream>>>(OFF, EIDX, edge_dist, g_means, g_stds,
                                     scale_p, H);
    k_repack<<<(EE + 255) / 256, 256, 0, stream>>>(EIDX, srcp, edge_attr);

    // layer loop
    for (int l = 0; l < LL; l++) {
        const float* sc = SCL + (size_t)(l - 1) * 1200;   // valid only l>0
        k_agg<<<(NN + 1) / 2, 320, 0, stream>>>(
            H, OFF, EIDX, ETAB + (size_t)l * 25 * DD,
            l > 0 ? sc : SCL, l > 0 ? sc + 600 : SCL, l > 0 ? 1 : 0, QB);
        k_mlp2<<<NN / 32, 256, 0, stream>>>(
            QB, W1P + (size_t)l * 10 * 640 * 32, mlp_b1 + (size_t)l * D2,
            W2P + (size_t)l * 19 * 384 * 32, mlp_b2 + (size_t)l * DD, H,
            REPS + (size_t)l * 38400);
        k_bnprep<<<2, 256, 0, stream>>>(REPS + (size_t)l * 38400,
                                        SCL + (size_t)l * 1200,
                                        bn_gamma + (size_t)l * DD,
                                        bn_beta + (size_t)l * DD);
    }

    // pooling; last BN folded into k_hgdiv
    hipMemsetAsync(CNT, 0, (size_t)GG * 4, stream);
    hipMemsetAsync(HG, 0, (size_t)GG * DD * 4, stream);
    k_count<<<(NN + 255) / 256, 256, 0, stream>>>(batch, CNT);
    k_pool<<<(NN + ROWS_PER - 1) / ROWS_PER, 320, 0, stream>>>(H, batch, HG);
    k_hgdiv<<<(GG * DD + 255) / 256, 256, 0, stream>>>(HG, CNT,
                                                       SCL + (size_t)4 * 1200);
    {
        dim3 grid((FEATN + 15) / 16, (GG + 15) / 16);
        k_gemm<<<grid, 256, 16 * DD * 4, stream>>>(HG, feat_w, feat_b, HFEAT, outp,
                                                   GG, DD, FEATN, 0);
    }
    {
        dim3 grid((FEATN + 15) / 16, (GG + 15) / 16);
        k_gemm<<<grid, 256, 16 * FEATN * 4, stream>>>(HFEAT, ol_w1, ol_b1, TMP, nullptr,
                                                      GG, FEATN, FEATN, 1);
    }
    {
        dim3 grid((OUT2 + 15) / 16, (GG + 15) / 16);
        k_gemm<<<grid, 256, 16 * FEATN * 4, stream>>>(TMP, ol_w2, ol_b2, nullptr,
                                                      outp + (size_t)GG * FEATN,
                                                      GG, FEATN, OUT2, 0);
    }
}